// Round 3
// baseline (2628.706 us; speedup 1.0000x reference)
//
#include <hip/hip_runtime.h>
#include <hip/hip_bf16.h>
#include <math.h>

// Problem constants
#define B_   8
#define D_   384
#define DC_  1024
#define NH_  8
#define NP_  4
#define DH_  48
#define NQ_  4096
#define NT_  730
#define NG_  729
#define GW_  27

typedef unsigned short u16;

__device__ __forceinline__ float bf2f(u16 u) { return __uint_as_float(((unsigned)u) << 16); }
__device__ __forceinline__ u16 f2bf(float f) {
    __hip_bfloat16 h = __float2bfloat16(f);
    return *reinterpret_cast<u16*>(&h);
}
__device__ __forceinline__ float rd(const float* p) { return *p; }
__device__ __forceinline__ float rd(const u16* p)   { return bf2f(*p); }
__device__ __forceinline__ void  wr(float* p, float v) { *p = v; }
__device__ __forceinline__ void  wr(u16* p, float v)   { *p = f2bf(v); }

// ---------------------------------------------------------------------------
// Tiled transpose: per batch src[R][C] -> dst[C][R]; Tin/Tout f32 or bf16.
// grid (C/32, R/32, B), block 256
// ---------------------------------------------------------------------------
template <typename Tin, typename Tout>
__global__ __launch_bounds__(256) void transpose_kernel(
    const Tin* __restrict__ src, Tout* __restrict__ dst, int R, int Cc)
{
    __shared__ float tile[32][33];
    const int b  = blockIdx.z;
    const int c0 = blockIdx.x << 5;
    const int r0 = blockIdx.y << 5;
    const Tin*  s = src + (size_t)b * R * Cc;
    Tout*       d = dst + (size_t)b * R * Cc;
    const int tx = threadIdx.x & 31, ty = threadIdx.x >> 5;  // ty 0..7
#pragma unroll
    for (int i = 0; i < 32; i += 8)
        tile[ty + i][tx] = rd(s + (size_t)(r0 + ty + i) * Cc + c0 + tx);
    __syncthreads();
#pragma unroll
    for (int i = 0; i < 32; i += 8)
        wr(d + (size_t)(c0 + ty + i) * R + r0 + tx, tile[tx][ty + i]);
}

// ---------------------------------------------------------------------------
// Row LayerNorm: Tin in [rows][width] -> bf16 out. width <= 1024. block 256.
// gamma/beta are f32 (global inputs).
// ---------------------------------------------------------------------------
template <typename Tin>
__global__ __launch_bounds__(256) void ln_kernel(
    const Tin* __restrict__ x, const float* __restrict__ g, const float* __restrict__ be,
    u16* __restrict__ out, int width)
{
    __shared__ float buf[1024];
    __shared__ float red[4][2];
    const size_t row = blockIdx.x;
    const Tin* xr = x + row * width;
    const int t = threadIdx.x;
    float s = 0.f, ss = 0.f;
    for (int i = t; i < width; i += 256) {
        float v = rd(xr + i); buf[i] = v; s += v; ss += v * v;
    }
#pragma unroll
    for (int o = 32; o > 0; o >>= 1) { s += __shfl_down(s, o); ss += __shfl_down(ss, o); }
    const int wave = t >> 6, lane = t & 63;
    if (lane == 0) { red[wave][0] = s; red[wave][1] = ss; }
    __syncthreads();
    if (t == 0) {
        float S = 0.f, SS = 0.f;
        for (int w = 0; w < 4; ++w) { S += red[w][0]; SS += red[w][1]; }
        float m = S / width;
        float v = SS / width - m * m;
        red[0][0] = m; red[0][1] = rsqrtf(v + 1e-5f);
    }
    __syncthreads();
    const float m = red[0][0], rs = red[0][1];
    u16* op = out + row * width;
    for (int i = t; i < width; i += 256)
        op[i] = f2bf((buf[i] - m) * rs * g[i] + be[i]);
}

// ---------------------------------------------------------------------------
// GEMM: C[M,N] = act(A[M,K] @ W[K,N] + bias[N]); A bf16, W/bias f32, C bf16,
// accumulate f32. ACT: 0 none, 1 exact gelu. BM=BN=64, BK=16, 256 thr, 4x4.
// ---------------------------------------------------------------------------
template <int ACT>
__global__ __launch_bounds__(256) void gemm_kernel(
    const u16* __restrict__ A, const float* __restrict__ W,
    const float* __restrict__ bias, u16* __restrict__ C,
    int M, int N, int K)
{
    __shared__ float As[16][64];
    __shared__ float Ws[16][64];
    const int m0 = blockIdx.x * 64;
    const int n0 = blockIdx.y * 64;
    const int t  = threadIdx.x;
    const int tx = t & 15, ty = t >> 4;
    const int ar = t >> 2;          // 0..63 row in A tile
    const int ak = (t & 3) << 2;    // 0,4,8,12
    const int wr2 = t >> 4;         // 0..15 k-row in W tile
    const int wc = (t & 15) << 2;   // col
    float acc[4][4] = {};
    for (int k0 = 0; k0 < K; k0 += 16) {
        const int gm = m0 + ar;
        if (gm < M) {
            ushort4 av = *reinterpret_cast<const ushort4*>(A + (size_t)gm * K + k0 + ak);
            As[ak + 0][ar] = bf2f(av.x); As[ak + 1][ar] = bf2f(av.y);
            As[ak + 2][ar] = bf2f(av.z); As[ak + 3][ar] = bf2f(av.w);
        } else {
            As[ak + 0][ar] = 0.f; As[ak + 1][ar] = 0.f;
            As[ak + 2][ar] = 0.f; As[ak + 3][ar] = 0.f;
        }
        const int gn = n0 + wc;
        if (gn < N) {
            float4 wv = *reinterpret_cast<const float4*>(W + (size_t)(k0 + wr2) * N + gn);
            Ws[wr2][wc + 0] = wv.x; Ws[wr2][wc + 1] = wv.y;
            Ws[wr2][wc + 2] = wv.z; Ws[wr2][wc + 3] = wv.w;
        } else {
            Ws[wr2][wc + 0] = 0.f; Ws[wr2][wc + 1] = 0.f;
            Ws[wr2][wc + 2] = 0.f; Ws[wr2][wc + 3] = 0.f;
        }
        __syncthreads();
#pragma unroll
        for (int k = 0; k < 16; ++k) {
            float4 a4 = *reinterpret_cast<const float4*>(&As[k][ty << 2]);
            float4 b4 = *reinterpret_cast<const float4*>(&Ws[k][tx << 2]);
            float a[4] = {a4.x, a4.y, a4.z, a4.w};
            float b[4] = {b4.x, b4.y, b4.z, b4.w};
#pragma unroll
            for (int i = 0; i < 4; ++i)
#pragma unroll
                for (int j = 0; j < 4; ++j)
                    acc[i][j] = fmaf(a[i], b[j], acc[i][j]);
        }
        __syncthreads();
    }
#pragma unroll
    for (int i = 0; i < 4; ++i) {
        const int gm = m0 + (ty << 2) + i;
        if (gm >= M) continue;
#pragma unroll
        for (int j = 0; j < 4; ++j) {
            const int gn = n0 + (tx << 2) + j;
            if (gn >= N) continue;
            float v = acc[i][j] + bias[gn];
            if (ACT == 1) v = 0.5f * v * (1.0f + erff(v * 0.70710678118654752f));
            C[(size_t)gm * N + gn] = f2bf(v);
        }
    }
}

// ---------------------------------------------------------------------------
// Scatter cp[B,730,384] (bf16) tokens 1..729 -> value[B,384,729] (f32)
// ---------------------------------------------------------------------------
__global__ __launch_bounds__(256) void scatter_value_kernel(
    const u16* __restrict__ cp, float* __restrict__ value)
{
    const int idx = blockIdx.x * 256 + threadIdx.x;
    const int total = B_ * NG_ * D_;
    if (idx >= total) return;
    const int c = idx % D_;
    const int p = (idx / D_) % NG_;
    const int b = idx / (D_ * NG_);
    value[((size_t)b * D_ + c) * NG_ + p] = bf2f(cp[((size_t)b * NT_ + 1 + p) * D_ + c]);
}

// ---------------------------------------------------------------------------
// Deformable attention: per block QT=4 queries. vn bf16, weights f32,
// value f32, out bf16.
// ---------------------------------------------------------------------------
#define QT 4
__global__ __launch_bounds__(128) void deform_kernel(
    const u16* __restrict__ vn, const float* __restrict__ value,
    const float* __restrict__ Woff, const float* __restrict__ boff,
    const float* __restrict__ Wattn, const float* __restrict__ battn,
    u16* __restrict__ out)
{
    __shared__ float vrow[QT][D_];
    __shared__ float sOff[QT][64];
    __shared__ float sAw[QT][32];
    __shared__ float sX0[QT][32], sY0[QT][32], sWx1[QT][32], sWy1[QT][32];

    const int blk = blockIdx.x;
    const int b   = blk / (NQ_ / QT);
    const int q0  = (blk % (NQ_ / QT)) * QT;
    const int t   = threadIdx.x;

    const u16* vr = vn + ((size_t)b * NQ_ + q0) * D_;
    for (int i = t; i < QT * D_; i += 128) {
        vrow[i / D_][i % D_] = bf2f(vr[i]);
    }
    __syncthreads();

    if (t < 96) {
        float acc[QT] = {0.f, 0.f, 0.f, 0.f};
        const bool isOff = (t < 64);
        const int j = isOff ? t : t - 64;
        for (int k = 0; k < D_; ++k) {
            float w = isOff ? Woff[k * 64 + j] : Wattn[k * 32 + j];
#pragma unroll
            for (int qq = 0; qq < QT; ++qq) acc[qq] += vrow[qq][k] * w;
        }
        if (isOff) {
            float bb = boff[j];
#pragma unroll
            for (int qq = 0; qq < QT; ++qq) sOff[qq][j] = acc[qq] + bb;
        } else {
            float bb = battn[j];
#pragma unroll
            for (int qq = 0; qq < QT; ++qq) sAw[qq][j] = acc[qq] + bb;
        }
    }
    __syncthreads();

    if (t < 32) {  // softmax over NP per (qq, h)
        const int qq = t >> 3, h = t & 7;
        float l0 = sAw[qq][h * 4 + 0], l1 = sAw[qq][h * 4 + 1];
        float l2 = sAw[qq][h * 4 + 2], l3 = sAw[qq][h * 4 + 3];
        float m = fmaxf(fmaxf(l0, l1), fmaxf(l2, l3));
        float e0 = expf(l0 - m), e1 = expf(l1 - m), e2 = expf(l2 - m), e3 = expf(l3 - m);
        float inv = 1.f / (e0 + e1 + e2 + e3);
        sAw[qq][h * 4 + 0] = e0 * inv; sAw[qq][h * 4 + 1] = e1 * inv;
        sAw[qq][h * 4 + 2] = e2 * inv; sAw[qq][h * 4 + 3] = e3 * inv;
    }
    {   // loc precompute, all 128 threads: (qq, point i)
        const int qq = t >> 5, i = t & 31;
        float ox = sOff[qq][2 * i], oy = sOff[qq][2 * i + 1];
        float gx = 2.f / (1.f + expf(-ox)) - 1.f;
        float gy = 2.f / (1.f + expf(-oy)) - 1.f;
        float ix = ((gx + 1.f) * (float)GW_ - 1.f) * 0.5f;
        float iy = ((gy + 1.f) * (float)GW_ - 1.f) * 0.5f;
        float x0 = floorf(ix), y0 = floorf(iy);
        sX0[qq][i] = x0; sY0[qq][i] = y0;
        sWx1[qq][i] = ix - x0; sWy1[qq][i] = iy - y0;
    }
    __syncthreads();

    for (int idx = t; idx < QT * D_; idx += 128) {
        const int qq = idx / D_, c = idx % D_, h = c / DH_;
        const float* vb = value + ((size_t)b * D_ + c) * NG_;
        float o = 0.f;
#pragma unroll
        for (int p = 0; p < NP_; ++p) {
            const int i = h * 4 + p;
            float x0 = sX0[qq][i], y0 = sY0[qq][i];
            float wx1 = sWx1[qq][i], wy1 = sWy1[qq][i];
            float wx0 = 1.f - wx1, wy0 = 1.f - wy1;
            int xi = (int)x0, yi = (int)y0;
            bool vx0 = (xi >= 0) & (xi < GW_), vx1 = (xi + 1 >= 0) & (xi + 1 < GW_);
            bool vy0 = (yi >= 0) & (yi < GW_), vy1 = (yi + 1 >= 0) & (yi + 1 < GW_);
            float v00 = (vx0 & vy0) ? vb[yi * GW_ + xi] : 0.f;
            float v10 = (vx1 & vy0) ? vb[yi * GW_ + xi + 1] : 0.f;
            float v01 = (vx0 & vy1) ? vb[(yi + 1) * GW_ + xi] : 0.f;
            float v11 = (vx1 & vy1) ? vb[(yi + 1) * GW_ + xi + 1] : 0.f;
            o += sAw[qq][i] * (v00 * wx0 * wy0 + v10 * wx1 * wy0 +
                               v01 * wx0 * wy1 + v11 * wx1 * wy1);
        }
        out[((size_t)b * NQ_ + q0 + qq) * D_ + c] = f2bf(o);
    }
}

// ---------------------------------------------------------------------------
// Gate: sigmoid(relu(vflat @ W_g1 + b_g1) @ W_g2 + b_g2) -> f32 (d_out region)
// ---------------------------------------------------------------------------
__global__ __launch_bounds__(128) void gate_kernel(
    const u16* __restrict__ vflat,
    const float* __restrict__ Wg1, const float* __restrict__ bg1,
    const float* __restrict__ Wg2, const float* __restrict__ bg2,
    float* __restrict__ gate_out)
{
    __shared__ float vrow[D_];
    __shared__ float sH[96];
    const size_t row = blockIdx.x;
    const int t = threadIdx.x;
    for (int i = t; i < D_; i += 128) vrow[i] = bf2f(vflat[row * D_ + i]);
    __syncthreads();
    if (t < 96) {
        float acc = 0.f;
        for (int k = 0; k < D_; ++k) acc += vrow[k] * Wg1[k * 96 + t];
        float h = acc + bg1[t];
        h = h > 0.f ? h : 0.f;
        sH[t] = h * Wg2[t];
    }
    __syncthreads();
    if (t == 0) {
        float s = bg2[0];
        for (int i = 0; i < 96; ++i) s += sH[i];
        gate_out[row] = 1.f / (1.f + expf(-s));
    }
}

// ---------------------------------------------------------------------------
// Fused output LN: x = vflat + gate*ffn; LN(ln_o) -> bf16 [B*Nq,384]
// gate read from d_out (f32), gamma/beta f32.
// ---------------------------------------------------------------------------
__global__ __launch_bounds__(128) void fused_ln_kernel(
    const u16* __restrict__ vflat, const float* __restrict__ gate,
    const u16* __restrict__ ffn,
    const float* __restrict__ g, const float* __restrict__ be,
    u16* __restrict__ outT)
{
    __shared__ float buf[D_];
    __shared__ float red[2][2];
    const size_t row = blockIdx.x;
    const int t = threadIdx.x;
    const float gv = gate[row];
    float s = 0.f, ss = 0.f;
    for (int i = t; i < D_; i += 128) {
        float v = bf2f(vflat[row * D_ + i]) + gv * bf2f(ffn[row * D_ + i]);
        buf[i] = v; s += v; ss += v * v;
    }
#pragma unroll
    for (int o = 32; o > 0; o >>= 1) { s += __shfl_down(s, o); ss += __shfl_down(ss, o); }
    const int wave = t >> 6, lane = t & 63;
    if (lane == 0) { red[wave][0] = s; red[wave][1] = ss; }
    __syncthreads();
    if (t == 0) {
        float S = red[0][0] + red[1][0], SS = red[0][1] + red[1][1];
        float m = S / (float)D_;
        float v = SS / (float)D_ - m * m;
        red[0][0] = m; red[0][1] = rsqrtf(v + 1e-5f);
    }
    __syncthreads();
    const float m = red[0][0], rs = red[0][1];
    u16* op = outT + row * D_;
    for (int i = t; i < D_; i += 128)
        op[i] = f2bf((buf[i] - m) * rs * g[i] + be[i]);
}

// ---------------------------------------------------------------------------
extern "C" void kernel_launch(void* const* d_in, const int* in_sizes, int n_in,
                              void* d_out, int out_size, void* d_ws, size_t ws_size,
                              hipStream_t stream)
{
    const float* visual = (const float*)d_in[0];
    const float* cut3r  = (const float*)d_in[1];
    const float* ln_v_g = (const float*)d_in[2];
    const float* ln_v_b = (const float*)d_in[3];
    const float* ln_c_g = (const float*)d_in[4];
    const float* ln_c_b = (const float*)d_in[5];
    const float* W_c1 = (const float*)d_in[6];
    const float* b_c1 = (const float*)d_in[7];
    const float* W_c2 = (const float*)d_in[8];
    const float* b_c2 = (const float*)d_in[9];
    const float* W_off = (const float*)d_in[10];
    const float* b_off = (const float*)d_in[11];
    const float* W_attn = (const float*)d_in[12];
    const float* b_attn = (const float*)d_in[13];
    const float* W_out = (const float*)d_in[14];
    const float* b_out = (const float*)d_in[15];
    const float* W_f1 = (const float*)d_in[16];
    const float* b_f1 = (const float*)d_in[17];
    const float* W_f2 = (const float*)d_in[18];
    const float* b_f2 = (const float*)d_in[19];
    const float* W_g1 = (const float*)d_in[20];
    const float* b_g1 = (const float*)d_in[21];
    const float* W_g2 = (const float*)d_in[22];
    const float* b_g2 = (const float*)d_in[23];
    const float* ln_o_g = (const float*)d_in[24];
    const float* ln_o_b = (const float*)d_in[25];

    // --- workspace layout (bytes), lifetime-based reuse; total ~84.8 MB ---
    // R0 [0, 25165824):        vflat bf16 [B,4096,384]         (steps 1..11)
    // R1 [25165824, 50331648): cn -> vn -> attn_out -> fusedT  (bf16)
    // R2 [50331648, 75497472): chid -> dout -> ffn             (bf16)
    // R3 [75497472, 88940544): cp bf16 + value f32, then hidden bf16
    char* ws = (char*)d_ws;
    u16*   vflat   = (u16*)(ws + 0);
    u16*   cn      = (u16*)(ws + 25165824);
    u16*   vn      = (u16*)(ws + 25165824);
    u16*   attn_out= (u16*)(ws + 25165824);
    u16*   fusedT  = (u16*)(ws + 25165824);
    u16*   chid    = (u16*)(ws + 50331648);
    u16*   dout    = (u16*)(ws + 50331648);
    u16*   ffn     = (u16*)(ws + 50331648);
    u16*   cp      = (u16*)(ws + 75497472);
    float* value   = (float*)(ws + 79982592);
    u16*   hidden  = (u16*)(ws + 75497472);

    float* out_fused = (float*)d_out;
    float* out_gate  = (float*)d_out + (size_t)B_ * D_ * NQ_;

    // 1. visual f32 [B,384,4096] -> vflat bf16 [B,4096,384]
    hipLaunchKernelGGL((transpose_kernel<float, u16>), dim3(128, 12, 8), dim3(256), 0, stream,
                       visual, vflat, 384, 4096);
    // 2. LN(cut3r f32) -> cn bf16
    hipLaunchKernelGGL((ln_kernel<float>), dim3(5840), dim3(256), 0, stream,
                       cut3r, ln_c_g, ln_c_b, cn, 1024);
    // 3. gelu(cn @ W_c1 + b_c1) -> chid
    hipLaunchKernelGGL((gemm_kernel<1>), dim3(92, 12), dim3(256), 0, stream,
                       cn, W_c1, b_c1, chid, 5840, 768, 1024);
    // 4. chid @ W_c2 + b_c2 -> cp
    hipLaunchKernelGGL((gemm_kernel<0>), dim3(92, 6), dim3(256), 0, stream,
                       chid, W_c2, b_c2, cp, 5840, 384, 768);
    // 5. scatter cp -> value [B,384,729] f32
    hipLaunchKernelGGL(scatter_value_kernel, dim3(8748), dim3(256), 0, stream, cp, value);
    // 6. LN(vflat bf16) -> vn bf16
    hipLaunchKernelGGL((ln_kernel<u16>), dim3(32768), dim3(256), 0, stream,
                       vflat, ln_v_g, ln_v_b, vn, 384);
    // 7. deformable attention -> dout bf16 [B*Nq,384]
    hipLaunchKernelGGL(deform_kernel, dim3(8192), dim3(128), 0, stream,
                       vn, value, W_off, b_off, W_attn, b_attn, dout);
    // 8. dout @ W_out + b_out -> attn_out
    hipLaunchKernelGGL((gemm_kernel<0>), dim3(512, 6), dim3(256), 0, stream,
                       dout, W_out, b_out, attn_out, 32768, 384, 384);
    // 9. FFN in 8 row-chunks (hidden buffer reuse; sequential on stream)
    for (int c = 0; c < 8; ++c) {
        hipLaunchKernelGGL((gemm_kernel<1>), dim3(64, 24), dim3(256), 0, stream,
                           attn_out + (size_t)c * 4096 * 384, W_f1, b_f1, hidden,
                           4096, 1536, 384);
        hipLaunchKernelGGL((gemm_kernel<0>), dim3(64, 6), dim3(256), 0, stream,
                           hidden, W_f2, b_f2, ffn + (size_t)c * 4096 * 384,
                           4096, 384, 1536);
    }
    // 10. gate -> f32 directly into d_out gate region
    hipLaunchKernelGGL(gate_kernel, dim3(32768), dim3(128), 0, stream,
                       vflat, W_g1, b_g1, W_g2, b_g2, out_gate);
    // 11. fused = LN(vflat + gate*ffn) -> fusedT bf16 [B,Nq,384]
    hipLaunchKernelGGL(fused_ln_kernel, dim3(32768), dim3(128), 0, stream,
                       vflat, out_gate, ffn, ln_o_g, ln_o_b, fusedT);
    // 12. fusedT bf16 [B,4096,384] -> d_out f32 [B,384,4096]
    hipLaunchKernelGGL((transpose_kernel<u16, float>), dim3(12, 128, 8), dim3(256), 0, stream,
                       fusedT, out_fused, 4096, 384);
}

// Round 4
// 2026.244 us; speedup vs baseline: 1.2973x; 1.2973x over previous
//
#include <hip/hip_runtime.h>
#include <hip/hip_bf16.h>
#include <math.h>

// Problem constants
#define B_   8
#define D_   384
#define DC_  1024
#define NH_  8
#define NP_  4
#define DH_  48
#define NQ_  4096
#define NT_  730
#define NG_  729
#define GW_  27

typedef unsigned short u16;

__device__ __forceinline__ float bf2f(u16 u) { return __uint_as_float(((unsigned)u) << 16); }
__device__ __forceinline__ u16 f2bf(float f) {
    __hip_bfloat16 h = __float2bfloat16(f);
    return *reinterpret_cast<u16*>(&h);
}
__device__ __forceinline__ float rd(const float* p) { return *p; }
__device__ __forceinline__ float rd(const u16* p)   { return bf2f(*p); }
__device__ __forceinline__ void  wr(float* p, float v) { *p = v; }
__device__ __forceinline__ void  wr(u16* p, float v)   { *p = f2bf(v); }

// ---------------------------------------------------------------------------
// Tiled transpose: per batch src[R][C] -> dst[C][R]; Tin/Tout f32 or bf16.
// grid (C/32, R/32, B), block 256
// ---------------------------------------------------------------------------
template <typename Tin, typename Tout>
__global__ __launch_bounds__(256) void transpose_kernel(
    const Tin* __restrict__ src, Tout* __restrict__ dst, int R, int Cc)
{
    __shared__ float tile[32][33];
    const int b  = blockIdx.z;
    const int c0 = blockIdx.x << 5;
    const int r0 = blockIdx.y << 5;
    const Tin*  s = src + (size_t)b * R * Cc;
    Tout*       d = dst + (size_t)b * R * Cc;
    const int tx = threadIdx.x & 31, ty = threadIdx.x >> 5;  // ty 0..7
#pragma unroll
    for (int i = 0; i < 32; i += 8)
        tile[ty + i][tx] = rd(s + (size_t)(r0 + ty + i) * Cc + c0 + tx);
    __syncthreads();
#pragma unroll
    for (int i = 0; i < 32; i += 8)
        wr(d + (size_t)(c0 + ty + i) * R + r0 + tx, tile[tx][ty + i]);
}

// ---------------------------------------------------------------------------
// Row LayerNorm: Tin in [rows][width] -> bf16 out. width <= 1024. block 256.
// ---------------------------------------------------------------------------
template <typename Tin>
__global__ __launch_bounds__(256) void ln_kernel(
    const Tin* __restrict__ x, const float* __restrict__ g, const float* __restrict__ be,
    u16* __restrict__ out, int width)
{
    __shared__ float buf[1024];
    __shared__ float red[4][2];
    const size_t row = blockIdx.x;
    const Tin* xr = x + row * width;
    const int t = threadIdx.x;
    float s = 0.f, ss = 0.f;
    for (int i = t; i < width; i += 256) {
        float v = rd(xr + i); buf[i] = v; s += v; ss += v * v;
    }
#pragma unroll
    for (int o = 32; o > 0; o >>= 1) { s += __shfl_down(s, o); ss += __shfl_down(ss, o); }
    const int wave = t >> 6, lane = t & 63;
    if (lane == 0) { red[wave][0] = s; red[wave][1] = ss; }
    __syncthreads();
    if (t == 0) {
        float S = 0.f, SS = 0.f;
        for (int w = 0; w < 4; ++w) { S += red[w][0]; SS += red[w][1]; }
        float m = S / width;
        float v = SS / width - m * m;
        red[0][0] = m; red[0][1] = rsqrtf(v + 1e-5f);
    }
    __syncthreads();
    const float m = red[0][0], rs = red[0][1];
    u16* op = out + row * width;
    for (int i = t; i < width; i += 256)
        op[i] = f2bf((buf[i] - m) * rs * g[i] + be[i]);
}

// ---------------------------------------------------------------------------
// GEMM: C[M,N] = act(A[M,K] @ W[K,N] + bias[N]); A bf16, W/bias f32,
// C f32 or bf16, accumulate f32. ACT: 0 none, 1 exact gelu, 2 relu.
// BM=BN=64, BK=16, 256 thr, 4x4 per thread.
// ---------------------------------------------------------------------------
template <int ACT, typename Tout>
__global__ __launch_bounds__(256) void gemm_kernel(
    const u16* __restrict__ A, const float* __restrict__ W,
    const float* __restrict__ bias, Tout* __restrict__ C,
    int M, int N, int K)
{
    __shared__ float As[16][64];
    __shared__ float Ws[16][64];
    const int m0 = blockIdx.x * 64;
    const int n0 = blockIdx.y * 64;
    const int t  = threadIdx.x;
    const int tx = t & 15, ty = t >> 4;
    const int ar = t >> 2;          // 0..63 row in A tile
    const int ak = (t & 3) << 2;    // 0,4,8,12
    const int wr2 = t >> 4;         // 0..15 k-row in W tile
    const int wc = (t & 15) << 2;   // col
    float acc[4][4] = {};
    for (int k0 = 0; k0 < K; k0 += 16) {
        const int gm = m0 + ar;
        if (gm < M) {
            ushort4 av = *reinterpret_cast<const ushort4*>(A + (size_t)gm * K + k0 + ak);
            As[ak + 0][ar] = bf2f(av.x); As[ak + 1][ar] = bf2f(av.y);
            As[ak + 2][ar] = bf2f(av.z); As[ak + 3][ar] = bf2f(av.w);
        } else {
            As[ak + 0][ar] = 0.f; As[ak + 1][ar] = 0.f;
            As[ak + 2][ar] = 0.f; As[ak + 3][ar] = 0.f;
        }
        const int gn = n0 + wc;
        if (gn < N) {
            float4 wv = *reinterpret_cast<const float4*>(W + (size_t)(k0 + wr2) * N + gn);
            Ws[wr2][wc + 0] = wv.x; Ws[wr2][wc + 1] = wv.y;
            Ws[wr2][wc + 2] = wv.z; Ws[wr2][wc + 3] = wv.w;
        } else {
            Ws[wr2][wc + 0] = 0.f; Ws[wr2][wc + 1] = 0.f;
            Ws[wr2][wc + 2] = 0.f; Ws[wr2][wc + 3] = 0.f;
        }
        __syncthreads();
#pragma unroll
        for (int k = 0; k < 16; ++k) {
            float4 a4 = *reinterpret_cast<const float4*>(&As[k][ty << 2]);
            float4 b4 = *reinterpret_cast<const float4*>(&Ws[k][tx << 2]);
            float a[4] = {a4.x, a4.y, a4.z, a4.w};
            float b[4] = {b4.x, b4.y, b4.z, b4.w};
#pragma unroll
            for (int i = 0; i < 4; ++i)
#pragma unroll
                for (int j = 0; j < 4; ++j)
                    acc[i][j] = fmaf(a[i], b[j], acc[i][j]);
        }
        __syncthreads();
    }
#pragma unroll
    for (int i = 0; i < 4; ++i) {
        const int gm = m0 + (ty << 2) + i;
        if (gm >= M) continue;
#pragma unroll
        for (int j = 0; j < 4; ++j) {
            const int gn = n0 + (tx << 2) + j;
            if (gn >= N) continue;
            float v = acc[i][j] + bias[gn];
            if (ACT == 1) v = 0.5f * v * (1.0f + erff(v * 0.70710678118654752f));
            if (ACT == 2) v = v > 0.f ? v : 0.f;
            wr(C + (size_t)gm * N + gn, v);
        }
    }
}

// ---------------------------------------------------------------------------
// Sampler: per block QT=4 queries. Reads precomputed projections
// off_buf [B*Nq,64], aw_buf [B*Nq,32] (f32), samples from cpf [B,730,384]
// (channel-contiguous -> coalesced corner reads). out bf16 [B*Nq,384].
// ---------------------------------------------------------------------------
#define QT 4
__global__ __launch_bounds__(128) void sample_kernel(
    const float* __restrict__ off_buf, const float* __restrict__ aw_buf,
    const float* __restrict__ cpf, u16* __restrict__ out)
{
    __shared__ float sAw[QT][32];
    __shared__ float sX0[QT][32], sY0[QT][32], sWx1[QT][32], sWy1[QT][32];

    const int blk = blockIdx.x;
    const int b   = blk / (NQ_ / QT);
    const int q0  = (blk % (NQ_ / QT)) * QT;
    const int t   = threadIdx.x;

    {   // loc precompute: t -> (qq, point i), 128 = QT*32 exactly
        const int qq = t >> 5, i = t & 31;
        const size_t row = (size_t)b * NQ_ + q0 + qq;
        float ox = off_buf[row * 64 + 2 * i], oy = off_buf[row * 64 + 2 * i + 1];
        float gx = 2.f / (1.f + expf(-ox)) - 1.f;
        float gy = 2.f / (1.f + expf(-oy)) - 1.f;
        float ix = ((gx + 1.f) * (float)GW_ - 1.f) * 0.5f;
        float iy = ((gy + 1.f) * (float)GW_ - 1.f) * 0.5f;
        float x0 = floorf(ix), y0 = floorf(iy);
        sX0[qq][i] = x0; sY0[qq][i] = y0;
        sWx1[qq][i] = ix - x0; sWy1[qq][i] = iy - y0;
    }
    if (t < 32) {  // softmax over NP per (qq, h)
        const int qq = t >> 3, h = t & 7;
        const size_t row = (size_t)b * NQ_ + q0 + qq;
        float l0 = aw_buf[row * 32 + h * 4 + 0], l1 = aw_buf[row * 32 + h * 4 + 1];
        float l2 = aw_buf[row * 32 + h * 4 + 2], l3 = aw_buf[row * 32 + h * 4 + 3];
        float m = fmaxf(fmaxf(l0, l1), fmaxf(l2, l3));
        float e0 = expf(l0 - m), e1 = expf(l1 - m), e2 = expf(l2 - m), e3 = expf(l3 - m);
        float inv = 1.f / (e0 + e1 + e2 + e3);
        sAw[qq][h * 4 + 0] = e0 * inv; sAw[qq][h * 4 + 1] = e1 * inv;
        sAw[qq][h * 4 + 2] = e2 * inv; sAw[qq][h * 4 + 3] = e3 * inv;
    }
    __syncthreads();

    // value[b, p, c] = cpf[b, 1+p, c]; p = y*27+x  (channel-contiguous)
    const float* vb = cpf + (size_t)b * NT_ * D_ + D_;
    for (int idx = t; idx < QT * D_; idx += 128) {
        const int qq = idx / D_, c = idx % D_, h = c / DH_;
        float o = 0.f;
#pragma unroll
        for (int p = 0; p < NP_; ++p) {
            const int i = h * 4 + p;
            float x0 = sX0[qq][i], y0 = sY0[qq][i];
            float wx1 = sWx1[qq][i], wy1 = sWy1[qq][i];
            float wx0 = 1.f - wx1, wy0 = 1.f - wy1;
            int xi = (int)x0, yi = (int)y0;
            bool vx0 = (xi >= 0) & (xi < GW_), vx1 = (xi + 1 >= 0) & (xi + 1 < GW_);
            bool vy0 = (yi >= 0) & (yi < GW_), vy1 = (yi + 1 >= 0) & (yi + 1 < GW_);
            float v00 = (vx0 & vy0) ? vb[((size_t)(yi * GW_ + xi)) * D_ + c] : 0.f;
            float v10 = (vx1 & vy0) ? vb[((size_t)(yi * GW_ + xi + 1)) * D_ + c] : 0.f;
            float v01 = (vx0 & vy1) ? vb[((size_t)((yi + 1) * GW_ + xi)) * D_ + c] : 0.f;
            float v11 = (vx1 & vy1) ? vb[((size_t)((yi + 1) * GW_ + xi + 1)) * D_ + c] : 0.f;
            o += sAw[qq][i] * (v00 * wx0 * wy0 + v10 * wx1 * wy0 +
                               v01 * wx0 * wy1 + v11 * wx1 * wy1);
        }
        out[((size_t)b * NQ_ + q0 + qq) * D_ + c] = f2bf(o);
    }
}

// ---------------------------------------------------------------------------
// Gate reduce: gate[row] = sigmoid(dot(gh[row,0:96], Wg2) + bg2).
// One wave per row, 4 rows per 256-thread block.
// ---------------------------------------------------------------------------
__global__ __launch_bounds__(256) void gate_reduce_kernel(
    const float* __restrict__ gh, const float* __restrict__ Wg2,
    const float* __restrict__ bg2, float* __restrict__ gate_out)
{
    const int wave = threadIdx.x >> 6, lane = threadIdx.x & 63;
    const size_t row = (size_t)blockIdx.x * 4 + wave;
    const float* h = gh + row * 96;
    float s = h[lane] * Wg2[lane];
    if (lane < 32) s += h[64 + lane] * Wg2[64 + lane];
#pragma unroll
    for (int o = 32; o > 0; o >>= 1) s += __shfl_down(s, o);
    if (lane == 0) gate_out[row] = 1.f / (1.f + expf(-(s + bg2[0])));
}

// ---------------------------------------------------------------------------
// Fused output LN: x = vflat + gate*ffn; LN(ln_o) -> bf16 [B*Nq,384]
// ---------------------------------------------------------------------------
__global__ __launch_bounds__(128) void fused_ln_kernel(
    const u16* __restrict__ vflat, const float* __restrict__ gate,
    const u16* __restrict__ ffn,
    const float* __restrict__ g, const float* __restrict__ be,
    u16* __restrict__ outT)
{
    __shared__ float buf[D_];
    __shared__ float red[2][2];
    const size_t row = blockIdx.x;
    const int t = threadIdx.x;
    const float gv = gate[row];
    float s = 0.f, ss = 0.f;
    for (int i = t; i < D_; i += 128) {
        float v = bf2f(vflat[row * D_ + i]) + gv * bf2f(ffn[row * D_ + i]);
        buf[i] = v; s += v; ss += v * v;
    }
#pragma unroll
    for (int o = 32; o > 0; o >>= 1) { s += __shfl_down(s, o); ss += __shfl_down(ss, o); }
    const int wave = t >> 6, lane = t & 63;
    if (lane == 0) { red[wave][0] = s; red[wave][1] = ss; }
    __syncthreads();
    if (t == 0) {
        float S = red[0][0] + red[1][0], SS = red[0][1] + red[1][1];
        float m = S / (float)D_;
        float v = SS / (float)D_ - m * m;
        red[0][0] = m; red[0][1] = rsqrtf(v + 1e-5f);
    }
    __syncthreads();
    const float m = red[0][0], rs = red[0][1];
    u16* op = outT + row * D_;
    for (int i = t; i < D_; i += 128)
        op[i] = f2bf((buf[i] - m) * rs * g[i] + be[i]);
}

// ---------------------------------------------------------------------------
extern "C" void kernel_launch(void* const* d_in, const int* in_sizes, int n_in,
                              void* d_out, int out_size, void* d_ws, size_t ws_size,
                              hipStream_t stream)
{
    const float* visual = (const float*)d_in[0];
    const float* cut3r  = (const float*)d_in[1];
    const float* ln_v_g = (const float*)d_in[2];
    const float* ln_v_b = (const float*)d_in[3];
    const float* ln_c_g = (const float*)d_in[4];
    const float* ln_c_b = (const float*)d_in[5];
    const float* W_c1 = (const float*)d_in[6];
    const float* b_c1 = (const float*)d_in[7];
    const float* W_c2 = (const float*)d_in[8];
    const float* b_c2 = (const float*)d_in[9];
    const float* W_off = (const float*)d_in[10];
    const float* b_off = (const float*)d_in[11];
    const float* W_attn = (const float*)d_in[12];
    const float* b_attn = (const float*)d_in[13];
    const float* W_out = (const float*)d_in[14];
    const float* b_out = (const float*)d_in[15];
    const float* W_f1 = (const float*)d_in[16];
    const float* b_f1 = (const float*)d_in[17];
    const float* W_f2 = (const float*)d_in[18];
    const float* b_f2 = (const float*)d_in[19];
    const float* W_g1 = (const float*)d_in[20];
    const float* b_g1 = (const float*)d_in[21];
    const float* W_g2 = (const float*)d_in[22];
    const float* b_g2 = (const float*)d_in[23];
    const float* ln_o_g = (const float*)d_in[24];
    const float* ln_o_b = (const float*)d_in[25];

    // --- workspace layout (bytes), lifetime-based reuse; high-water ~84.5 MB ---
    // R0 [0, 25165824):        vflat bf16 [B,4096,384]         (steps 1..11)
    // R1 [25165824, 50331648): cn -> vn -> attn_out -> fusedT  (bf16)
    // R2 [50331648, 75497472): chid -> dout -> ffn             (bf16)
    // R3 [75497472, 84467712): cpf f32 [B,730,384]; then hidden bf16 [4096,1536]
    char* ws = (char*)d_ws;
    u16*   vflat   = (u16*)(ws + 0);
    u16*   cn      = (u16*)(ws + 25165824);
    u16*   vn      = (u16*)(ws + 25165824);
    u16*   attn_out= (u16*)(ws + 25165824);
    u16*   fusedT  = (u16*)(ws + 25165824);
    u16*   chid    = (u16*)(ws + 50331648);
    u16*   dout    = (u16*)(ws + 50331648);
    u16*   ffn     = (u16*)(ws + 50331648);
    float* cpf     = (float*)(ws + 75497472);
    u16*   hidden  = (u16*)(ws + 75497472);   // reuse after cpf dead (step 7)

    // d_out used as f32 scratch before being overwritten by steps 10-12:
    float* dout_f   = (float*)d_out;
    float* off_buf  = dout_f;                 // [32768,64] = 2,097,152 f
    float* aw_buf   = dout_f + 2097152;       // [32768,32] = 1,048,576 f
    float* gate_hid = dout_f + 3145728;       // [32768,96] = 3,145,728 f
    float* out_fused = dout_f;
    float* out_gate  = dout_f + (size_t)B_ * D_ * NQ_;

    // 1. visual f32 [B,384,4096] -> vflat bf16 [B,4096,384]
    hipLaunchKernelGGL((transpose_kernel<float, u16>), dim3(128, 12, 8), dim3(256), 0, stream,
                       visual, vflat, 384, 4096);
    // 2. LN(cut3r f32) -> cn bf16
    hipLaunchKernelGGL((ln_kernel<float>), dim3(5840), dim3(256), 0, stream,
                       cut3r, ln_c_g, ln_c_b, cn, 1024);
    // 3. gelu(cn @ W_c1 + b_c1) -> chid bf16
    hipLaunchKernelGGL((gemm_kernel<1, u16>), dim3(92, 12), dim3(256), 0, stream,
                       cn, W_c1, b_c1, chid, 5840, 768, 1024);
    // 4. chid @ W_c2 + b_c2 -> cpf f32 [B,730,384] (sampled directly later)
    hipLaunchKernelGGL((gemm_kernel<0, float>), dim3(92, 6), dim3(256), 0, stream,
                       chid, W_c2, b_c2, cpf, 5840, 384, 768);
    // 5. LN(vflat bf16) -> vn bf16
    hipLaunchKernelGGL((ln_kernel<u16>), dim3(32768), dim3(256), 0, stream,
                       vflat, ln_v_g, ln_v_b, vn, 384);
    // 6. projection GEMMs -> d_out scratch (f32)
    hipLaunchKernelGGL((gemm_kernel<0, float>), dim3(512, 1), dim3(256), 0, stream,
                       vn, W_off, b_off, off_buf, 32768, 64, 384);
    hipLaunchKernelGGL((gemm_kernel<0, float>), dim3(512, 1), dim3(256), 0, stream,
                       vn, W_attn, b_attn, aw_buf, 32768, 32, 384);
    // 7. sampler -> dout bf16 [B*Nq,384]
    hipLaunchKernelGGL(sample_kernel, dim3(8192), dim3(128), 0, stream,
                       off_buf, aw_buf, cpf, dout);
    // 8. dout @ W_out + b_out -> attn_out bf16
    hipLaunchKernelGGL((gemm_kernel<0, u16>), dim3(512, 6), dim3(256), 0, stream,
                       dout, W_out, b_out, attn_out, 32768, 384, 384);
    // 9. FFN in 8 row-chunks (hidden buffer reuse; sequential on stream)
    for (int c = 0; c < 8; ++c) {
        hipLaunchKernelGGL((gemm_kernel<1, u16>), dim3(64, 24), dim3(256), 0, stream,
                           attn_out + (size_t)c * 4096 * 384, W_f1, b_f1, hidden,
                           4096, 1536, 384);
        hipLaunchKernelGGL((gemm_kernel<0, u16>), dim3(64, 6), dim3(256), 0, stream,
                           hidden, W_f2, b_f2, ffn + (size_t)c * 4096 * 384,
                           4096, 384, 1536);
    }
    // 10. gate: relu(vflat @ W_g1 + b_g1) -> gate_hid; reduce -> out_gate f32
    hipLaunchKernelGGL((gemm_kernel<2, float>), dim3(512, 2), dim3(256), 0, stream,
                       vflat, W_g1, b_g1, gate_hid, 32768, 96, 384);
    hipLaunchKernelGGL(gate_reduce_kernel, dim3(8192), dim3(256), 0, stream,
                       gate_hid, W_g2, b_g2, out_gate);
    // 11. fused = LN(vflat + gate*ffn) -> fusedT bf16 [B,Nq,384]
    hipLaunchKernelGGL(fused_ln_kernel, dim3(32768), dim3(128), 0, stream,
                       vflat, out_gate, ffn, ln_o_g, ln_o_b, fusedT);
    // 12. fusedT bf16 [B,4096,384] -> d_out f32 [B,384,4096]
    hipLaunchKernelGGL((transpose_kernel<u16, float>), dim3(12, 128, 8), dim3(256), 0, stream,
                       fusedT, out_fused, 4096, 384);
}

// Round 5
// 932.471 us; speedup vs baseline: 2.8191x; 2.1730x over previous
//
#include <hip/hip_runtime.h>
#include <hip/hip_bf16.h>
#include <math.h>

// Problem constants
#define B_   8
#define D_   384
#define DC_  1024
#define NH_  8
#define NP_  4
#define DH_  48
#define NQ_  4096
#define NT_  730
#define NG_  729
#define GW_  27

typedef unsigned short u16;
typedef __attribute__((ext_vector_type(8))) short s8bf;   // 8 bf16 (4 VGPR)
typedef __attribute__((ext_vector_type(4))) float f32x4;  // MFMA accumulator

__device__ __forceinline__ float bf2f(u16 u) { return __uint_as_float(((unsigned)u) << 16); }
__device__ __forceinline__ u16 f2bf(float f) {
    __hip_bfloat16 h = __float2bfloat16(f);
    return *reinterpret_cast<u16*>(&h);
}
__device__ __forceinline__ float rd(const float* p) { return *p; }
__device__ __forceinline__ float rd(const u16* p)   { return bf2f(*p); }
__device__ __forceinline__ void  wr(float* p, float v) { *p = v; }
__device__ __forceinline__ void  wr(u16* p, float v)   { *p = f2bf(v); }

// ---------------------------------------------------------------------------
// Tiled transpose: per batch src[R][C] -> dst[C][R]; Tin/Tout f32 or bf16.
// grid (C/32, R/32, B), block 256. Also used for weight f32[K,N]->bf16[N,K].
// ---------------------------------------------------------------------------
template <typename Tin, typename Tout>
__global__ __launch_bounds__(256) void transpose_kernel(
    const Tin* __restrict__ src, Tout* __restrict__ dst, int R, int Cc)
{
    __shared__ float tile[32][33];
    const int b  = blockIdx.z;
    const int c0 = blockIdx.x << 5;
    const int r0 = blockIdx.y << 5;
    const Tin*  s = src + (size_t)b * R * Cc;
    Tout*       d = dst + (size_t)b * R * Cc;
    const int tx = threadIdx.x & 31, ty = threadIdx.x >> 5;  // ty 0..7
#pragma unroll
    for (int i = 0; i < 32; i += 8)
        tile[ty + i][tx] = rd(s + (size_t)(r0 + ty + i) * Cc + c0 + tx);
    __syncthreads();
#pragma unroll
    for (int i = 0; i < 32; i += 8)
        wr(d + (size_t)(c0 + ty + i) * R + r0 + tx, tile[tx][ty + i]);
}

// ---------------------------------------------------------------------------
// Row LayerNorm: Tin in [rows][width] -> bf16 out. width <= 1024. block 256.
// ---------------------------------------------------------------------------
template <typename Tin>
__global__ __launch_bounds__(256) void ln_kernel(
    const Tin* __restrict__ x, const float* __restrict__ g, const float* __restrict__ be,
    u16* __restrict__ out, int width)
{
    __shared__ float buf[1024];
    __shared__ float red[4][2];
    const size_t row = blockIdx.x;
    const Tin* xr = x + row * width;
    const int t = threadIdx.x;
    float s = 0.f, ss = 0.f;
    for (int i = t; i < width; i += 256) {
        float v = rd(xr + i); buf[i] = v; s += v; ss += v * v;
    }
#pragma unroll
    for (int o = 32; o > 0; o >>= 1) { s += __shfl_down(s, o); ss += __shfl_down(ss, o); }
    const int wave = t >> 6, lane = t & 63;
    if (lane == 0) { red[wave][0] = s; red[wave][1] = ss; }
    __syncthreads();
    if (t == 0) {
        float S = 0.f, SS = 0.f;
        for (int w = 0; w < 4; ++w) { S += red[w][0]; SS += red[w][1]; }
        float m = S / width;
        float v = SS / width - m * m;
        red[0][0] = m; red[0][1] = rsqrtf(v + 1e-5f);
    }
    __syncthreads();
    const float m = red[0][0], rs = red[0][1];
    u16* op = out + row * width;
    for (int i = t; i < width; i += 256)
        op[i] = f2bf((buf[i] - m) * rs * g[i] + be[i]);
}

// ---------------------------------------------------------------------------
// MFMA GEMM: C[M,N] = act(A[M,K] @ W[K,N] + bias[N])
// A bf16 [M,K]; Wt bf16 [N,K] (pre-transposed); bias f32; C f32 or bf16.
// BM=BN=128, BK=32. 256 threads = 4 waves in 2x2, each wave 64x64 output
// (4x4 fragments of v_mfma_f32_16x16x32_bf16). K must be a multiple of 32.
// LDS: fragment-major granules [ks 0..3][row 0..127] of 16B -> conflict-free
// (uniform 8-phase) for both staging writes and fragment reads.
// ACT: 0 none, 1 exact gelu, 2 relu.
// ---------------------------------------------------------------------------
template <int ACT, typename Tout>
__global__ __launch_bounds__(256) void mfma_gemm(
    const u16* __restrict__ A, const u16* __restrict__ Wt,
    const float* __restrict__ bias, Tout* __restrict__ C,
    int M, int N, int K)
{
    __shared__ u16 As[512 * 8];   // granule g = ks*128+row -> As[g*8 .. g*8+7]
    __shared__ u16 Bs[512 * 8];
    const int t    = threadIdx.x;
    const int m0   = blockIdx.x * 128;
    const int n0   = blockIdx.y * 128;
    const int lane = t & 63;
    const int wave = t >> 6;
    const int wm   = (wave >> 1) * 64;    // wave row offset in tile
    const int wn   = (wave & 1) * 64;     // wave col offset in tile
    const int lr   = lane & 15;
    const int lks  = lane >> 4;

    // staging map: granule g in [0,512): row = g>>2, ks = g&3
    const int srow = t >> 2, sks = t & 3;
    const bool aok0 = (m0 + srow)      < M;
    const bool aok1 = (m0 + 64 + srow) < M;
    const bool bok0 = (n0 + srow)      < N;
    const bool bok1 = (n0 + 64 + srow) < N;

    f32x4 acc[4][4] = {};

    for (int k0 = 0; k0 < K; k0 += 32) {
        s8bf va0 = {}, va1 = {}, vb0 = {}, vb1 = {};
        if (aok0) va0 = *reinterpret_cast<const s8bf*>(A + (size_t)(m0 + srow) * K + k0 + sks * 8);
        if (aok1) va1 = *reinterpret_cast<const s8bf*>(A + (size_t)(m0 + 64 + srow) * K + k0 + sks * 8);
        if (bok0) vb0 = *reinterpret_cast<const s8bf*>(Wt + (size_t)(n0 + srow) * K + k0 + sks * 8);
        if (bok1) vb1 = *reinterpret_cast<const s8bf*>(Wt + (size_t)(n0 + 64 + srow) * K + k0 + sks * 8);
        *reinterpret_cast<s8bf*>(&As[(size_t)(sks * 128 + srow) * 8])      = va0;
        *reinterpret_cast<s8bf*>(&As[(size_t)(sks * 128 + 64 + srow) * 8]) = va1;
        *reinterpret_cast<s8bf*>(&Bs[(size_t)(sks * 128 + srow) * 8])      = vb0;
        *reinterpret_cast<s8bf*>(&Bs[(size_t)(sks * 128 + 64 + srow) * 8]) = vb1;
        __syncthreads();

        s8bf af[4], bfr[4];
#pragma unroll
        for (int i = 0; i < 4; ++i) {
            af[i]  = *reinterpret_cast<const s8bf*>(&As[(size_t)(lks * 128 + wm + i * 16 + lr) * 8]);
            bfr[i] = *reinterpret_cast<const s8bf*>(&Bs[(size_t)(lks * 128 + wn + i * 16 + lr) * 8]);
        }
#pragma unroll
        for (int i = 0; i < 4; ++i)
#pragma unroll
            for (int j = 0; j < 4; ++j)
                acc[i][j] = __builtin_amdgcn_mfma_f32_16x16x32_bf16(af[i], bfr[j], acc[i][j], 0, 0, 0);
        __syncthreads();
    }

    // epilogue: D row = (lane>>4)*4 + r, col = lane&15 (m89-verified layout)
#pragma unroll
    for (int i = 0; i < 4; ++i) {
        const int gr0 = m0 + wm + i * 16 + (lane >> 4) * 4;
#pragma unroll
        for (int j = 0; j < 4; ++j) {
            const int gc = n0 + wn + j * 16 + lr;
            if (gc >= N) continue;
            const float bb = bias[gc];
#pragma unroll
            for (int r = 0; r < 4; ++r) {
                const int gr = gr0 + r;
                if (gr >= M) continue;
                float v = acc[i][j][r] + bb;
                if (ACT == 1) v = 0.5f * v * (1.0f + erff(v * 0.70710678118654752f));
                if (ACT == 2) v = v > 0.f ? v : 0.f;
                wr(C + (size_t)gr * N + gc, v);
            }
        }
    }
}

// ---------------------------------------------------------------------------
// Sampler: per block QT=4 queries. Reads precomputed projections
// off_buf [B*Nq,64], aw_buf [B*Nq,32] (f32), samples from cpf [B,730,384]
// (channel-contiguous -> coalesced corner reads). out bf16 [B*Nq,384].
// ---------------------------------------------------------------------------
#define QT 4
__global__ __launch_bounds__(128) void sample_kernel(
    const float* __restrict__ off_buf, const float* __restrict__ aw_buf,
    const float* __restrict__ cpf, u16* __restrict__ out)
{
    __shared__ float sAw[QT][32];
    __shared__ float sX0[QT][32], sY0[QT][32], sWx1[QT][32], sWy1[QT][32];

    const int blk = blockIdx.x;
    const int b   = blk / (NQ_ / QT);
    const int q0  = (blk % (NQ_ / QT)) * QT;
    const int t   = threadIdx.x;

    {   // loc precompute: t -> (qq, point i), 128 = QT*32 exactly
        const int qq = t >> 5, i = t & 31;
        const size_t row = (size_t)b * NQ_ + q0 + qq;
        float ox = off_buf[row * 64 + 2 * i], oy = off_buf[row * 64 + 2 * i + 1];
        float gx = 2.f / (1.f + expf(-ox)) - 1.f;
        float gy = 2.f / (1.f + expf(-oy)) - 1.f;
        float ix = ((gx + 1.f) * (float)GW_ - 1.f) * 0.5f;
        float iy = ((gy + 1.f) * (float)GW_ - 1.f) * 0.5f;
        float x0 = floorf(ix), y0 = floorf(iy);
        sX0[qq][i] = x0; sY0[qq][i] = y0;
        sWx1[qq][i] = ix - x0; sWy1[qq][i] = iy - y0;
    }
    if (t < 32) {  // softmax over NP per (qq, h)
        const int qq = t >> 3, h = t & 7;
        const size_t row = (size_t)b * NQ_ + q0 + qq;
        float l0 = aw_buf[row * 32 + h * 4 + 0], l1 = aw_buf[row * 32 + h * 4 + 1];
        float l2 = aw_buf[row * 32 + h * 4 + 2], l3 = aw_buf[row * 32 + h * 4 + 3];
        float m = fmaxf(fmaxf(l0, l1), fmaxf(l2, l3));
        float e0 = expf(l0 - m), e1 = expf(l1 - m), e2 = expf(l2 - m), e3 = expf(l3 - m);
        float inv = 1.f / (e0 + e1 + e2 + e3);
        sAw[qq][h * 4 + 0] = e0 * inv; sAw[qq][h * 4 + 1] = e1 * inv;
        sAw[qq][h * 4 + 2] = e2 * inv; sAw[qq][h * 4 + 3] = e3 * inv;
    }
    __syncthreads();

    // value[b, p, c] = cpf[b, 1+p, c]; p = y*27+x  (channel-contiguous)
    const float* vb = cpf + (size_t)b * NT_ * D_ + D_;
    for (int idx = t; idx < QT * D_; idx += 128) {
        const int qq = idx / D_, c = idx % D_, h = c / DH_;
        float o = 0.f;
#pragma unroll
        for (int p = 0; p < NP_; ++p) {
            const int i = h * 4 + p;
            float x0 = sX0[qq][i], y0 = sY0[qq][i];
            float wx1 = sWx1[qq][i], wy1 = sWy1[qq][i];
            float wx0 = 1.f - wx1, wy0 = 1.f - wy1;
            int xi = (int)x0, yi = (int)y0;
            bool vx0 = (xi >= 0) & (xi < GW_), vx1 = (xi + 1 >= 0) & (xi + 1 < GW_);
            bool vy0 = (yi >= 0) & (yi < GW_), vy1 = (yi + 1 >= 0) & (yi + 1 < GW_);
            float v00 = (vx0 & vy0) ? vb[((size_t)(yi * GW_ + xi)) * D_ + c] : 0.f;
            float v10 = (vx1 & vy0) ? vb[((size_t)(yi * GW_ + xi + 1)) * D_ + c] : 0.f;
            float v01 = (vx0 & vy1) ? vb[((size_t)((yi + 1) * GW_ + xi)) * D_ + c] : 0.f;
            float v11 = (vx1 & vy1) ? vb[((size_t)((yi + 1) * GW_ + xi + 1)) * D_ + c] : 0.f;
            o += sAw[qq][i] * (v00 * wx0 * wy0 + v10 * wx1 * wy0 +
                               v01 * wx0 * wy1 + v11 * wx1 * wy1);
        }
        out[((size_t)b * NQ_ + q0 + qq) * D_ + c] = f2bf(o);
    }
}

// ---------------------------------------------------------------------------
// Gate reduce: gate[row] = sigmoid(dot(gh[row,0:96], Wg2) + bg2).
// One wave per row, 4 rows per 256-thread block.
// ---------------------------------------------------------------------------
__global__ __launch_bounds__(256) void gate_reduce_kernel(
    const float* __restrict__ gh, const float* __restrict__ Wg2,
    const float* __restrict__ bg2, float* __restrict__ gate_out)
{
    const int wave = threadIdx.x >> 6, lane = threadIdx.x & 63;
    const size_t row = (size_t)blockIdx.x * 4 + wave;
    const float* h = gh + row * 96;
    float s = h[lane] * Wg2[lane];
    if (lane < 32) s += h[64 + lane] * Wg2[64 + lane];
#pragma unroll
    for (int o = 32; o > 0; o >>= 1) s += __shfl_down(s, o);
    if (lane == 0) gate_out[row] = 1.f / (1.f + expf(-(s + bg2[0])));
}

// ---------------------------------------------------------------------------
// Fused output LN: x = vflat + gate*ffn; LN(ln_o) -> bf16 [B*Nq,384]
// ---------------------------------------------------------------------------
__global__ __launch_bounds__(128) void fused_ln_kernel(
    const u16* __restrict__ vflat, const float* __restrict__ gate,
    const u16* __restrict__ ffn,
    const float* __restrict__ g, const float* __restrict__ be,
    u16* __restrict__ outT)
{
    __shared__ float buf[D_];
    __shared__ float red[2][2];
    const size_t row = blockIdx.x;
    const int t = threadIdx.x;
    const float gv = gate[row];
    float s = 0.f, ss = 0.f;
    for (int i = t; i < D_; i += 128) {
        float v = bf2f(vflat[row * D_ + i]) + gv * bf2f(ffn[row * D_ + i]);
        buf[i] = v; s += v; ss += v * v;
    }
#pragma unroll
    for (int o = 32; o > 0; o >>= 1) { s += __shfl_down(s, o); ss += __shfl_down(ss, o); }
    const int wave = t >> 6, lane = t & 63;
    if (lane == 0) { red[wave][0] = s; red[wave][1] = ss; }
    __syncthreads();
    if (t == 0) {
        float S = red[0][0] + red[1][0], SS = red[0][1] + red[1][1];
        float m = S / (float)D_;
        float v = SS / (float)D_ - m * m;
        red[0][0] = m; red[0][1] = rsqrtf(v + 1e-5f);
    }
    __syncthreads();
    const float m = red[0][0], rs = red[0][1];
    u16* op = outT + row * D_;
    for (int i = t; i < D_; i += 128)
        op[i] = f2bf((buf[i] - m) * rs * g[i] + be[i]);
}

// ---------------------------------------------------------------------------
extern "C" void kernel_launch(void* const* d_in, const int* in_sizes, int n_in,
                              void* d_out, int out_size, void* d_ws, size_t ws_size,
                              hipStream_t stream)
{
    const float* visual = (const float*)d_in[0];
    const float* cut3r  = (const float*)d_in[1];
    const float* ln_v_g = (const float*)d_in[2];
    const float* ln_v_b = (const float*)d_in[3];
    const float* ln_c_g = (const float*)d_in[4];
    const float* ln_c_b = (const float*)d_in[5];
    const float* W_c1 = (const float*)d_in[6];
    const float* b_c1 = (const float*)d_in[7];
    const float* W_c2 = (const float*)d_in[8];
    const float* b_c2 = (const float*)d_in[9];
    const float* W_off = (const float*)d_in[10];
    const float* b_off = (const float*)d_in[11];
    const float* W_attn = (const float*)d_in[12];
    const float* b_attn = (const float*)d_in[13];
    const float* W_out = (const float*)d_in[14];
    const float* b_out = (const float*)d_in[15];
    const float* W_f1 = (const float*)d_in[16];
    const float* b_f1 = (const float*)d_in[17];
    const float* W_f2 = (const float*)d_in[18];
    const float* b_f2 = (const float*)d_in[19];
    const float* W_g1 = (const float*)d_in[20];
    const float* b_g1 = (const float*)d_in[21];
    const float* W_g2 = (const float*)d_in[22];
    const float* b_g2 = (const float*)d_in[23];
    const float* ln_o_g = (const float*)d_in[24];
    const float* ln_o_b = (const float*)d_in[25];

    // --- workspace layout (bytes), lifetime-based reuse; high-water ~80.6 MB ---
    // R0 [0, 25165824):        vflat bf16 [B,4096,384]         (steps 1..11)
    // R1 [25165824, 50331648): cn -> vn -> attn_out -> fusedT  (bf16)
    // R2 [50331648, 75497472): chid -> dout -> ffn             (bf16)
    // R3 [75497472, 84467712): cpf f32 [B,730,384]
    char* ws = (char*)d_ws;
    u16*   vflat   = (u16*)(ws + 0);
    u16*   cn      = (u16*)(ws + 25165824);
    u16*   vn      = (u16*)(ws + 25165824);
    u16*   attn_out= (u16*)(ws + 25165824);
    u16*   fusedT  = (u16*)(ws + 25165824);
    u16*   chid    = (u16*)(ws + 50331648);
    u16*   dout    = (u16*)(ws + 50331648);
    u16*   ffn     = (u16*)(ws + 50331648);
    float* cpf     = (float*)(ws + 75497472);

    // --- d_out as scratch (fully overwritten by steps 10-12) ---
    // floats:   off_buf [0, 2097152) | aw_buf [2097152, 3145728) |
    //           hidden(bf16, bytes [12582912, 25165824)) then gate_hid same region
    // bytes:    Wt pool [25165824, 30130176)
    // out_gate: floats [12582912, 12615680) == bytes [50331648, 50462720)
    float* dout_f   = (float*)d_out;
    float* off_buf  = dout_f;                  // [32768,64] f32
    float* aw_buf   = dout_f + 2097152;        // [32768,32] f32
    float* gate_hid = dout_f + 3145728;        // [32768,96] f32 (step 10 only)
    u16*   hidden   = (u16*)((char*)d_out + 12582912);  // [4096,1536] bf16 (FFN)
    char*  wtp      = (char*)d_out + 25165824;          // bf16 W^T pool (~4.96 MB)
    u16* wt_c1   = (u16*)wtp;                  // [768][1024]
    u16* wt_c2   = wt_c1 + 786432;             // [384][768]
    u16* wt_out  = wt_c2 + 294912;             // [384][384]
    u16* wt_f1   = wt_out + 147456;            // [1536][384]
    u16* wt_f2   = wt_f1 + 589824;             // [384][1536]
    u16* wt_g1   = wt_f2 + 589824;             // [96][384]
    u16* wt_off  = wt_g1 + 36864;              // [64][384]
    u16* wt_attn = wt_off + 24576;             // [32][384]
    float* out_fused = dout_f;
    float* out_gate  = dout_f + (size_t)B_ * D_ * NQ_;

    // 0. weight conversion: W f32 [K,N] -> Wt bf16 [N,K]  (transpose, R=K, C=N)
    hipLaunchKernelGGL((transpose_kernel<float, u16>), dim3(24, 32, 1), dim3(256), 0, stream, W_c1, wt_c1, 1024, 768);
    hipLaunchKernelGGL((transpose_kernel<float, u16>), dim3(12, 24, 1), dim3(256), 0, stream, W_c2, wt_c2, 768, 384);
    hipLaunchKernelGGL((transpose_kernel<float, u16>), dim3(12, 12, 1), dim3(256), 0, stream, W_out, wt_out, 384, 384);
    hipLaunchKernelGGL((transpose_kernel<float, u16>), dim3(48, 12, 1), dim3(256), 0, stream, W_f1, wt_f1, 384, 1536);
    hipLaunchKernelGGL((transpose_kernel<float, u16>), dim3(12, 48, 1), dim3(256), 0, stream, W_f2, wt_f2, 1536, 384);
    hipLaunchKernelGGL((transpose_kernel<float, u16>), dim3(3, 12, 1), dim3(256), 0, stream, W_g1, wt_g1, 384, 96);
    hipLaunchKernelGGL((transpose_kernel<float, u16>), dim3(2, 12, 1), dim3(256), 0, stream, W_off, wt_off, 384, 64);
    hipLaunchKernelGGL((transpose_kernel<float, u16>), dim3(1, 12, 1), dim3(256), 0, stream, W_attn, wt_attn, 384, 32);

    // 1. visual f32 [B,384,4096] -> vflat bf16 [B,4096,384]
    hipLaunchKernelGGL((transpose_kernel<float, u16>), dim3(128, 12, 8), dim3(256), 0, stream,
                       visual, vflat, 384, 4096);
    // 2. LN(cut3r f32) -> cn bf16
    hipLaunchKernelGGL((ln_kernel<float>), dim3(5840), dim3(256), 0, stream,
                       cut3r, ln_c_g, ln_c_b, cn, 1024);
    // 3. gelu(cn @ W_c1 + b_c1) -> chid bf16   [5840 x 768 x 1024]
    hipLaunchKernelGGL((mfma_gemm<1, u16>), dim3(46, 6), dim3(256), 0, stream,
                       cn, wt_c1, b_c1, chid, 5840, 768, 1024);
    // 4. chid @ W_c2 + b_c2 -> cpf f32 [B,730,384]   [5840 x 384 x 768]
    hipLaunchKernelGGL((mfma_gemm<0, float>), dim3(46, 3), dim3(256), 0, stream,
                       chid, wt_c2, b_c2, cpf, 5840, 384, 768);
    // 5. LN(vflat bf16) -> vn bf16
    hipLaunchKernelGGL((ln_kernel<u16>), dim3(32768), dim3(256), 0, stream,
                       vflat, ln_v_g, ln_v_b, vn, 384);
    // 6. projection GEMMs -> d_out scratch (f32)   [32768 x {64,32} x 384]
    hipLaunchKernelGGL((mfma_gemm<0, float>), dim3(256, 1), dim3(256), 0, stream,
                       vn, wt_off, b_off, off_buf, 32768, 64, 384);
    hipLaunchKernelGGL((mfma_gemm<0, float>), dim3(256, 1), dim3(256), 0, stream,
                       vn, wt_attn, b_attn, aw_buf, 32768, 32, 384);
    // 7. sampler -> dout bf16 [B*Nq,384]
    hipLaunchKernelGGL(sample_kernel, dim3(8192), dim3(128), 0, stream,
                       off_buf, aw_buf, cpf, dout);
    // 8. dout @ W_out + b_out -> attn_out bf16   [32768 x 384 x 384]
    hipLaunchKernelGGL((mfma_gemm<0, u16>), dim3(256, 3), dim3(256), 0, stream,
                       dout, wt_out, b_out, attn_out, 32768, 384, 384);
    // 9. FFN in 8 row-chunks; hidden lives in d_out scratch
    for (int c = 0; c < 8; ++c) {
        hipLaunchKernelGGL((mfma_gemm<1, u16>), dim3(32, 12), dim3(256), 0, stream,
                           attn_out + (size_t)c * 4096 * 384, wt_f1, b_f1, hidden,
                           4096, 1536, 384);
        hipLaunchKernelGGL((mfma_gemm<0, u16>), dim3(32, 3), dim3(256), 0, stream,
                           hidden, wt_f2, b_f2, ffn + (size_t)c * 4096 * 384,
                           4096, 384, 1536);
    }
    // 10. gate: relu(vflat @ W_g1 + b_g1) -> gate_hid; reduce -> out_gate f32
    hipLaunchKernelGGL((mfma_gemm<2, float>), dim3(256, 1), dim3(256), 0, stream,
                       vflat, wt_g1, b_g1, gate_hid, 32768, 96, 384);
    hipLaunchKernelGGL(gate_reduce_kernel, dim3(8192), dim3(256), 0, stream,
                       gate_hid, W_g2, b_g2, out_gate);
    // 11. fused = LN(vflat + gate*ffn) -> fusedT bf16 [B,Nq,384]
    hipLaunchKernelGGL(fused_ln_kernel, dim3(32768), dim3(128), 0, stream,
                       vflat, out_gate, ffn, ln_o_g, ln_o_b, fusedT);
    // 12. fusedT bf16 [B,4096,384] -> d_out f32 [B,384,4096]
    hipLaunchKernelGGL((transpose_kernel<u16, float>), dim3(12, 128, 8), dim3(256), 0, stream,
                       fusedT, out_fused, 4096, 384);
}

// Round 6
// 602.277 us; speedup vs baseline: 4.3646x; 1.5482x over previous
//
#include <hip/hip_runtime.h>
#include <hip/hip_bf16.h>
#include <math.h>

// Problem constants
#define B_   8
#define D_   384
#define DC_  1024
#define NH_  8
#define NP_  4
#define DH_  48
#define NQ_  4096
#define NT_  730
#define NG_  729
#define GW_  27

typedef unsigned short u16;
typedef __attribute__((ext_vector_type(8))) short s8bf;   // 8 bf16 (4 VGPR)
typedef __attribute__((ext_vector_type(4))) float f32x4;  // MFMA accumulator

__device__ __forceinline__ float bf2f(u16 u) { return __uint_as_float(((unsigned)u) << 16); }
__device__ __forceinline__ u16 f2bf(float f) {
    __hip_bfloat16 h = __float2bfloat16(f);
    return *reinterpret_cast<u16*>(&h);
}
__device__ __forceinline__ float rd(const float* p) { return *p; }
__device__ __forceinline__ float rd(const u16* p)   { return bf2f(*p); }
__device__ __forceinline__ void  wr(float* p, float v) { *p = v; }
__device__ __forceinline__ void  wr(u16* p, float v)   { *p = f2bf(v); }
__device__ __forceinline__ void fmacc4(float4& o, const float4 v, float w) {
    o.x = fmaf(v.x, w, o.x); o.y = fmaf(v.y, w, o.y);
    o.z = fmaf(v.z, w, o.z); o.w = fmaf(v.w, w, o.w);
}

// ---------------------------------------------------------------------------
// Tiled transpose: per batch src[R][C] -> dst[C][R]; Tin/Tout f32 or bf16.
// grid (C/32, R/32, B), block 256. Also used for weight f32[K,N]->bf16[N,K].
// ---------------------------------------------------------------------------
template <typename Tin, typename Tout>
__global__ __launch_bounds__(256) void transpose_kernel(
    const Tin* __restrict__ src, Tout* __restrict__ dst, int R, int Cc)
{
    __shared__ float tile[32][33];
    const int b  = blockIdx.z;
    const int c0 = blockIdx.x << 5;
    const int r0 = blockIdx.y << 5;
    const Tin*  s = src + (size_t)b * R * Cc;
    Tout*       d = dst + (size_t)b * R * Cc;
    const int tx = threadIdx.x & 31, ty = threadIdx.x >> 5;  // ty 0..7
#pragma unroll
    for (int i = 0; i < 32; i += 8)
        tile[ty + i][tx] = rd(s + (size_t)(r0 + ty + i) * Cc + c0 + tx);
    __syncthreads();
#pragma unroll
    for (int i = 0; i < 32; i += 8)
        wr(d + (size_t)(c0 + ty + i) * R + r0 + tx, tile[tx][ty + i]);
}

// ---------------------------------------------------------------------------
// Row LayerNorm: Tin in [rows][width] -> bf16 out. width <= 1024. block 256.
// ---------------------------------------------------------------------------
template <typename Tin>
__global__ __launch_bounds__(256) void ln_kernel(
    const Tin* __restrict__ x, const float* __restrict__ g, const float* __restrict__ be,
    u16* __restrict__ out, int width)
{
    __shared__ float buf[1024];
    __shared__ float red[4][2];
    const size_t row = blockIdx.x;
    const Tin* xr = x + row * width;
    const int t = threadIdx.x;
    float s = 0.f, ss = 0.f;
    for (int i = t; i < width; i += 256) {
        float v = rd(xr + i); buf[i] = v; s += v; ss += v * v;
    }
#pragma unroll
    for (int o = 32; o > 0; o >>= 1) { s += __shfl_down(s, o); ss += __shfl_down(ss, o); }
    const int wave = t >> 6, lane = t & 63;
    if (lane == 0) { red[wave][0] = s; red[wave][1] = ss; }
    __syncthreads();
    if (t == 0) {
        float S = 0.f, SS = 0.f;
        for (int w = 0; w < 4; ++w) { S += red[w][0]; SS += red[w][1]; }
        float m = S / width;
        float v = SS / width - m * m;
        red[0][0] = m; red[0][1] = rsqrtf(v + 1e-5f);
    }
    __syncthreads();
    const float m = red[0][0], rs = red[0][1];
    u16* op = out + row * width;
    for (int i = t; i < width; i += 256)
        op[i] = f2bf((buf[i] - m) * rs * g[i] + be[i]);
}

// ---------------------------------------------------------------------------
// MFMA GEMM with register prefetch: C[M,N] = act(A[M,K] @ W[K,N] + bias[N])
// A bf16 [M,K]; Wt bf16 [N,K] (pre-transposed); bias f32; C f32 or bf16.
// BM=BN=128, BK=32. 256 threads = 4 waves 2x2, each wave 64x64 (4x4 frags of
// v_mfma_f32_16x16x32_bf16). K % 32 == 0. LDS fragment-major 16B granules
// [ks 0..3][row 0..127] -> conflict-free staging writes and fragment reads.
// Next K-step's global loads issue right after barrier 1 -> overlap with MFMA.
// ACT: 0 none, 1 exact gelu, 2 relu.
// ---------------------------------------------------------------------------
template <int ACT, typename Tout>
__global__ __launch_bounds__(256) void mfma_gemm(
    const u16* __restrict__ A, const u16* __restrict__ Wt,
    const float* __restrict__ bias, Tout* __restrict__ C,
    int M, int N, int K)
{
    __shared__ u16 As[512 * 8];   // granule g = ks*128+row -> As[g*8 .. g*8+7]
    __shared__ u16 Bs[512 * 8];
    const int t    = threadIdx.x;
    const int m0   = blockIdx.x * 128;
    const int n0   = blockIdx.y * 128;
    const int lane = t & 63;
    const int wave = t >> 6;
    const int wm   = (wave >> 1) * 64;    // wave row offset in tile
    const int wn   = (wave & 1) * 64;     // wave col offset in tile
    const int lr   = lane & 15;
    const int lks  = lane >> 4;

    // staging map: thread t stages rows (srow, srow+64) of k-slice sks
    const int srow = t >> 2, sks = t & 3;
    const bool aok0 = (m0 + srow)      < M;
    const bool aok1 = (m0 + 64 + srow) < M;
    const bool bok0 = (n0 + srow)      < N;
    const bool bok1 = (n0 + 64 + srow) < N;
    const u16* ap0 = A  + (size_t)(m0 + srow)      * K + sks * 8;
    const u16* ap1 = A  + (size_t)(m0 + 64 + srow) * K + sks * 8;
    const u16* bp0 = Wt + (size_t)(n0 + srow)      * K + sks * 8;
    const u16* bp1 = Wt + (size_t)(n0 + 64 + srow) * K + sks * 8;

    f32x4 acc[4][4] = {};

    s8bf va0 = {}, va1 = {}, vb0 = {}, vb1 = {};
    if (aok0) va0 = *reinterpret_cast<const s8bf*>(ap0);
    if (aok1) va1 = *reinterpret_cast<const s8bf*>(ap1);
    if (bok0) vb0 = *reinterpret_cast<const s8bf*>(bp0);
    if (bok1) vb1 = *reinterpret_cast<const s8bf*>(bp1);

    for (int k0 = 0; k0 < K; k0 += 32) {
        *reinterpret_cast<s8bf*>(&As[(size_t)(sks * 128 + srow) * 8])      = va0;
        *reinterpret_cast<s8bf*>(&As[(size_t)(sks * 128 + 64 + srow) * 8]) = va1;
        *reinterpret_cast<s8bf*>(&Bs[(size_t)(sks * 128 + srow) * 8])      = vb0;
        *reinterpret_cast<s8bf*>(&Bs[(size_t)(sks * 128 + 64 + srow) * 8]) = vb1;
        __syncthreads();

        // prefetch next K-step while MFMA phase runs
        s8bf na0 = {}, na1 = {}, nb0 = {}, nb1 = {};
        if (k0 + 32 < K) {
            if (aok0) na0 = *reinterpret_cast<const s8bf*>(ap0 + k0 + 32);
            if (aok1) na1 = *reinterpret_cast<const s8bf*>(ap1 + k0 + 32);
            if (bok0) nb0 = *reinterpret_cast<const s8bf*>(bp0 + k0 + 32);
            if (bok1) nb1 = *reinterpret_cast<const s8bf*>(bp1 + k0 + 32);
        }

        s8bf af[4], bfr[4];
#pragma unroll
        for (int i = 0; i < 4; ++i) {
            af[i]  = *reinterpret_cast<const s8bf*>(&As[(size_t)(lks * 128 + wm + i * 16 + lr) * 8]);
            bfr[i] = *reinterpret_cast<const s8bf*>(&Bs[(size_t)(lks * 128 + wn + i * 16 + lr) * 8]);
        }
#pragma unroll
        for (int i = 0; i < 4; ++i)
#pragma unroll
            for (int j = 0; j < 4; ++j)
                acc[i][j] = __builtin_amdgcn_mfma_f32_16x16x32_bf16(af[i], bfr[j], acc[i][j], 0, 0, 0);
        __syncthreads();
        va0 = na0; va1 = na1; vb0 = nb0; vb1 = nb1;
    }

    // epilogue: D row = (lane>>4)*4 + r, col = lane&15 (m89-verified layout)
#pragma unroll
    for (int i = 0; i < 4; ++i) {
        const int gr0 = m0 + wm + i * 16 + (lane >> 4) * 4;
#pragma unroll
        for (int j = 0; j < 4; ++j) {
            const int gc = n0 + wn + j * 16 + lr;
            if (gc >= N) continue;
            const float bb = bias[gc];
#pragma unroll
            for (int r = 0; r < 4; ++r) {
                const int gr = gr0 + r;
                if (gr >= M) continue;
                float v = acc[i][j][r] + bb;
                if (ACT == 1) v = 0.5f * v * (1.0f + erff(v * 0.70710678118654752f));
                if (ACT == 2) v = v > 0.f ? v : 0.f;
                wr(C + (size_t)gr * N + gc, v);
            }
        }
    }
}

// ---------------------------------------------------------------------------
// Bias concat for fused off+attn projection: b_cat[0:64)=b_off, [64:96)=b_attn
// ---------------------------------------------------------------------------
__global__ __launch_bounds__(128) void concat_bias_kernel(
    const float* __restrict__ b_off, const float* __restrict__ b_attn,
    float* __restrict__ b_cat)
{
    const int t = threadIdx.x;
    if (t < 64) b_cat[t] = b_off[t];
    else if (t < 96) b_cat[t] = b_attn[t - 64];
}

// ---------------------------------------------------------------------------
// Sampler (float4-vectorized channels): per block QT=8 queries, 256 threads.
// proj [B*Nq,96] f32: cols 0..63 = offsets, 64..95 = attn logits.
// cpf [B,730,384] f32 channel-contiguous -> float4 gathers. out bf16.
// ---------------------------------------------------------------------------
__global__ __launch_bounds__(256) void sample_kernel(
    const float* __restrict__ proj, const float* __restrict__ cpf,
    u16* __restrict__ out)
{
    __shared__ float sAw[8][32];
    __shared__ float sX0[8][32], sY0[8][32], sWx1[8][32], sWy1[8][32];

    const int blk = blockIdx.x;
    const int b   = blk / (NQ_ / 8);
    const int q0  = (blk % (NQ_ / 8)) * 8;
    const int t   = threadIdx.x;

    {   // loc precompute: t -> (qq, point i), 256 = 8*32 exactly
        const int qq = t >> 5, i = t & 31;
        const size_t row = (size_t)b * NQ_ + q0 + qq;
        float ox = proj[row * 96 + 2 * i], oy = proj[row * 96 + 2 * i + 1];
        float gx = 2.f / (1.f + expf(-ox)) - 1.f;
        float gy = 2.f / (1.f + expf(-oy)) - 1.f;
        float ix = ((gx + 1.f) * (float)GW_ - 1.f) * 0.5f;
        float iy = ((gy + 1.f) * (float)GW_ - 1.f) * 0.5f;
        float x0 = floorf(ix), y0 = floorf(iy);
        sX0[qq][i] = x0; sY0[qq][i] = y0;
        sWx1[qq][i] = ix - x0; sWy1[qq][i] = iy - y0;
    }
    if (t < 64) {  // softmax over NP per (qq, h)
        const int qq = t >> 3, h = t & 7;
        const size_t row = (size_t)b * NQ_ + q0 + qq;
        const float* lg = proj + row * 96 + 64 + h * 4;
        float l0 = lg[0], l1 = lg[1], l2 = lg[2], l3 = lg[3];
        float m = fmaxf(fmaxf(l0, l1), fmaxf(l2, l3));
        float e0 = expf(l0 - m), e1 = expf(l1 - m), e2 = expf(l2 - m), e3 = expf(l3 - m);
        float inv = 1.f / (e0 + e1 + e2 + e3);
        sAw[qq][h * 4 + 0] = e0 * inv; sAw[qq][h * 4 + 1] = e1 * inv;
        sAw[qq][h * 4 + 2] = e2 * inv; sAw[qq][h * 4 + 3] = e3 * inv;
    }
    __syncthreads();

    // value[b, p, c] = cpf[b, 1+p, c]; float4 view: [729 tokens][96]
    const float4* vb4 = reinterpret_cast<const float4*>(cpf + (size_t)b * NT_ * D_ + D_);
    for (int idx = t; idx < 8 * 96; idx += 256) {   // 3 iterations
        const int qq = idx / 96, c4 = idx % 96, h = c4 / 12;   // 12 float4 per head
        float4 o = make_float4(0.f, 0.f, 0.f, 0.f);
#pragma unroll
        for (int p = 0; p < NP_; ++p) {
            const int i = h * 4 + p;
            float x0 = sX0[qq][i], y0 = sY0[qq][i];
            float wx1 = sWx1[qq][i], wy1 = sWy1[qq][i];
            float wx0 = 1.f - wx1, wy0 = 1.f - wy1;
            int xi = (int)x0, yi = (int)y0;
            bool vx0 = (xi >= 0) & (xi < GW_), vx1 = (xi + 1 >= 0) & (xi + 1 < GW_);
            bool vy0 = (yi >= 0) & (yi < GW_), vy1 = (yi + 1 >= 0) & (yi + 1 < GW_);
            const float aw = sAw[qq][i];
            if (vx0 & vy0) fmacc4(o, vb4[(size_t)(yi * GW_ + xi) * 96 + c4],       aw * wx0 * wy0);
            if (vx1 & vy0) fmacc4(o, vb4[(size_t)(yi * GW_ + xi + 1) * 96 + c4],   aw * wx1 * wy0);
            if (vx0 & vy1) fmacc4(o, vb4[(size_t)((yi + 1) * GW_ + xi) * 96 + c4], aw * wx0 * wy1);
            if (vx1 & vy1) fmacc4(o, vb4[(size_t)((yi + 1) * GW_ + xi + 1) * 96 + c4], aw * wx1 * wy1);
        }
        ushort4 pk;
        pk.x = f2bf(o.x); pk.y = f2bf(o.y); pk.z = f2bf(o.z); pk.w = f2bf(o.w);
        *reinterpret_cast<ushort4*>(&out[((size_t)b * NQ_ + q0 + qq) * D_ + c4 * 4]) = pk;
    }
}

// ---------------------------------------------------------------------------
// Gate reduce: gate[row] = sigmoid(dot(gh[row,0:96], Wg2) + bg2).
// One wave per row, 4 rows per 256-thread block.
// ---------------------------------------------------------------------------
__global__ __launch_bounds__(256) void gate_reduce_kernel(
    const float* __restrict__ gh, const float* __restrict__ Wg2,
    const float* __restrict__ bg2, float* __restrict__ gate_out)
{
    const int wave = threadIdx.x >> 6, lane = threadIdx.x & 63;
    const size_t row = (size_t)blockIdx.x * 4 + wave;
    const float* h = gh + row * 96;
    float s = h[lane] * Wg2[lane];
    if (lane < 32) s += h[64 + lane] * Wg2[64 + lane];
#pragma unroll
    for (int o = 32; o > 0; o >>= 1) s += __shfl_down(s, o);
    if (lane == 0) gate_out[row] = 1.f / (1.f + expf(-(s + bg2[0])));
}

// ---------------------------------------------------------------------------
// Fused output LN: x = vflat + gate*ffn; LN(ln_o) -> bf16 [B*Nq,384]
// ---------------------------------------------------------------------------
__global__ __launch_bounds__(128) void fused_ln_kernel(
    const u16* __restrict__ vflat, const float* __restrict__ gate,
    const u16* __restrict__ ffn,
    const float* __restrict__ g, const float* __restrict__ be,
    u16* __restrict__ outT)
{
    __shared__ float buf[D_];
    __shared__ float red[2][2];
    const size_t row = blockIdx.x;
    const int t = threadIdx.x;
    const float gv = gate[row];
    float s = 0.f, ss = 0.f;
    for (int i = t; i < D_; i += 128) {
        float v = bf2f(vflat[row * D_ + i]) + gv * bf2f(ffn[row * D_ + i]);
        buf[i] = v; s += v; ss += v * v;
    }
#pragma unroll
    for (int o = 32; o > 0; o >>= 1) { s += __shfl_down(s, o); ss += __shfl_down(ss, o); }
    const int wave = t >> 6, lane = t & 63;
    if (lane == 0) { red[wave][0] = s; red[wave][1] = ss; }
    __syncthreads();
    if (t == 0) {
        float S = red[0][0] + red[1][0], SS = red[0][1] + red[1][1];
        float m = S / (float)D_;
        float v = SS / (float)D_ - m * m;
        red[0][0] = m; red[0][1] = rsqrtf(v + 1e-5f);
    }
    __syncthreads();
    const float m = red[0][0], rs = red[0][1];
    u16* op = outT + row * D_;
    for (int i = t; i < D_; i += 128)
        op[i] = f2bf((buf[i] - m) * rs * g[i] + be[i]);
}

// ---------------------------------------------------------------------------
extern "C" void kernel_launch(void* const* d_in, const int* in_sizes, int n_in,
                              void* d_out, int out_size, void* d_ws, size_t ws_size,
                              hipStream_t stream)
{
    const float* visual = (const float*)d_in[0];
    const float* cut3r  = (const float*)d_in[1];
    const float* ln_v_g = (const float*)d_in[2];
    const float* ln_v_b = (const float*)d_in[3];
    const float* ln_c_g = (const float*)d_in[4];
    const float* ln_c_b = (const float*)d_in[5];
    const float* W_c1 = (const float*)d_in[6];
    const float* b_c1 = (const float*)d_in[7];
    const float* W_c2 = (const float*)d_in[8];
    const float* b_c2 = (const float*)d_in[9];
    const float* W_off = (const float*)d_in[10];
    const float* b_off = (const float*)d_in[11];
    const float* W_attn = (const float*)d_in[12];
    const float* b_attn = (const float*)d_in[13];
    const float* W_out = (const float*)d_in[14];
    const float* b_out = (const float*)d_in[15];
    const float* W_f1 = (const float*)d_in[16];
    const float* b_f1 = (const float*)d_in[17];
    const float* W_f2 = (const float*)d_in[18];
    const float* b_f2 = (const float*)d_in[19];
    const float* W_g1 = (const float*)d_in[20];
    const float* b_g1 = (const float*)d_in[21];
    const float* W_g2 = (const float*)d_in[22];
    const float* b_g2 = (const float*)d_in[23];
    const float* ln_o_g = (const float*)d_in[24];
    const float* ln_o_b = (const float*)d_in[25];

    // --- workspace layout (bytes), lifetime-based reuse; high-water ~84.5 MB ---
    // R0 [0, 25165824):        vflat bf16 [B,4096,384]         (steps 1..11)
    // R1 [25165824, 50331648): cn -> vn -> attn_out -> fusedT  (bf16)
    // R2 [50331648, 75497472): chid -> dout -> ffn             (bf16)
    // R3 [75497472, 84467712): cpf f32 [B,730,384]
    char* ws = (char*)d_ws;
    u16*   vflat   = (u16*)(ws + 0);
    u16*   cn      = (u16*)(ws + 25165824);
    u16*   vn      = (u16*)(ws + 25165824);
    u16*   attn_out= (u16*)(ws + 25165824);
    u16*   fusedT  = (u16*)(ws + 25165824);
    u16*   chid    = (u16*)(ws + 50331648);
    u16*   dout    = (u16*)(ws + 50331648);
    u16*   ffn     = (u16*)(ws + 50331648);
    float* cpf     = (float*)(ws + 75497472);

    // --- d_out as scratch (fully overwritten by steps 10-12) ---
    // proj_buf f32 [32768,96]   bytes [0, 12582912)      (steps 6-7)
    // b_cat    f32 [96]         bytes [12582912, 12583296) (step 6)
    // hidden   bf16 [8192,1536] bytes [0, 25165824)      (step 9, per chunk)
    // gate_hid f32 [32768,96]   bytes [0, 12582912)      (step 10)
    // wt pool  bf16 (~4.96 MB)  bytes [25165824, 30130176) (steps 0-10)
    // out_gate f32 [32768]      bytes [50331648, 50462720) (steps 10-12, final)
    float* dout_f   = (float*)d_out;
    float* proj_buf = dout_f;
    float* b_cat    = dout_f + 3145728;
    u16*   hidden   = (u16*)d_out;
    float* gate_hid = dout_f;
    char*  wtp      = (char*)d_out + 25165824;
    u16* wt_c1   = (u16*)wtp;                  // [768][1024]
    u16* wt_c2   = wt_c1 + 786432;             // [384][768]
    u16* wt_out  = wt_c2 + 294912;             // [384][384]
    u16* wt_f1   = wt_out + 147456;            // [1536][384]
    u16* wt_f2   = wt_f1 + 589824;             // [384][1536]
    u16* wt_g1   = wt_f2 + 589824;             // [96][384]
    u16* wt_off  = wt_g1 + 36864;              // [64][384]  \ contiguous [96][384]
    u16* wt_attn = wt_off + 24576;             // [32][384]  /
    float* out_fused = dout_f;
    float* out_gate  = dout_f + (size_t)B_ * D_ * NQ_;

    // 0. weight conversion: W f32 [K,N] -> Wt bf16 [N,K]
    hipLaunchKernelGGL((transpose_kernel<float, u16>), dim3(24, 32, 1), dim3(256), 0, stream, W_c1, wt_c1, 1024, 768);
    hipLaunchKernelGGL((transpose_kernel<float, u16>), dim3(12, 24, 1), dim3(256), 0, stream, W_c2, wt_c2, 768, 384);
    hipLaunchKernelGGL((transpose_kernel<float, u16>), dim3(12, 12, 1), dim3(256), 0, stream, W_out, wt_out, 384, 384);
    hipLaunchKernelGGL((transpose_kernel<float, u16>), dim3(48, 12, 1), dim3(256), 0, stream, W_f1, wt_f1, 384, 1536);
    hipLaunchKernelGGL((transpose_kernel<float, u16>), dim3(12, 48, 1), dim3(256), 0, stream, W_f2, wt_f2, 1536, 384);
    hipLaunchKernelGGL((transpose_kernel<float, u16>), dim3(3, 12, 1), dim3(256), 0, stream, W_g1, wt_g1, 384, 96);
    hipLaunchKernelGGL((transpose_kernel<float, u16>), dim3(2, 12, 1), dim3(256), 0, stream, W_off, wt_off, 384, 64);
    hipLaunchKernelGGL((transpose_kernel<float, u16>), dim3(1, 12, 1), dim3(256), 0, stream, W_attn, wt_attn, 384, 32);
    hipLaunchKernelGGL(concat_bias_kernel, dim3(1), dim3(128), 0, stream, b_off, b_attn, b_cat);

    // 1. visual f32 [B,384,4096] -> vflat bf16 [B,4096,384]
    hipLaunchKernelGGL((transpose_kernel<float, u16>), dim3(128, 12, 8), dim3(256), 0, stream,
                       visual, vflat, 384, 4096);
    // 2. LN(cut3r f32) -> cn bf16
    hipLaunchKernelGGL((ln_kernel<float>), dim3(5840), dim3(256), 0, stream,
                       cut3r, ln_c_g, ln_c_b, cn, 1024);
    // 3. gelu(cn @ W_c1 + b_c1) -> chid bf16   [5840 x 768 x 1024]
    hipLaunchKernelGGL((mfma_gemm<1, u16>), dim3(46, 6), dim3(256), 0, stream,
                       cn, wt_c1, b_c1, chid, 5840, 768, 1024);
    // 4. chid @ W_c2 + b_c2 -> cpf f32 [B,730,384]   [5840 x 384 x 768]
    hipLaunchKernelGGL((mfma_gemm<0, float>), dim3(46, 3), dim3(256), 0, stream,
                       chid, wt_c2, b_c2, cpf, 5840, 384, 768);
    // 5. LN(vflat bf16) -> vn bf16
    hipLaunchKernelGGL((ln_kernel<u16>), dim3(32768), dim3(256), 0, stream,
                       vflat, ln_v_g, ln_v_b, vn, 384);
    // 6. fused off+attn projection -> proj_buf f32 [32768 x 96 x 384]
    hipLaunchKernelGGL((mfma_gemm<0, float>), dim3(256, 1), dim3(256), 0, stream,
                       vn, wt_off, b_cat, proj_buf, 32768, 96, 384);
    // 7. sampler -> dout bf16 [B*Nq,384]
    hipLaunchKernelGGL(sample_kernel, dim3(4096), dim3(256), 0, stream,
                       proj_buf, cpf, dout);
    // 8. dout @ W_out + b_out -> attn_out bf16   [32768 x 384 x 384]
    hipLaunchKernelGGL((mfma_gemm<0, u16>), dim3(256, 3), dim3(256), 0, stream,
                       dout, wt_out, b_out, attn_out, 32768, 384, 384);
    // 9. FFN in 4 row-chunks of 8192; hidden in d_out scratch
    for (int c = 0; c < 4; ++c) {
        hipLaunchKernelGGL((mfma_gemm<1, u16>), dim3(64, 12), dim3(256), 0, stream,
                           attn_out + (size_t)c * 8192 * 384, wt_f1, b_f1, hidden,
                           8192, 1536, 384);
        hipLaunchKernelGGL((mfma_gemm<0, u16>), dim3(64, 3), dim3(256), 0, stream,
                           hidden, wt_f2, b_f2, ffn + (size_t)c * 8192 * 384,
                           8192, 384, 1536);
    }
    // 10. gate: relu(vflat @ W_g1 + b_g1) -> gate_hid; reduce -> out_gate f32
    hipLaunchKernelGGL((mfma_gemm<2, float>), dim3(256, 1), dim3(256), 0, stream,
                       vflat, wt_g1, b_g1, gate_hid, 32768, 96, 384);
    hipLaunchKernelGGL(gate_reduce_kernel, dim3(8192), dim3(256), 0, stream,
                       gate_hid, W_g2, b_g2, out_gate);
    // 11. fused = LN(vflat + gate*ffn) -> fusedT bf16 [B,Nq,384]
    hipLaunchKernelGGL(fused_ln_kernel, dim3(32768), dim3(128), 0, stream,
                       vflat, out_gate, ffn, ln_o_g, ln_o_b, fusedT);
    // 12. fusedT bf16 [B,4096,384] -> d_out f32 [B,384,4096]
    hipLaunchKernelGGL((transpose_kernel<u16, float>), dim3(12, 128, 8), dim3(256), 0, stream,
                       fusedT, out_fused, 4096, 384);
}

// Round 7
// 484.155 us; speedup vs baseline: 5.4295x; 1.2440x over previous
//
#include <hip/hip_runtime.h>
#include <hip/hip_bf16.h>
#include <math.h>

// Problem constants
#define B_   8
#define D_   384
#define DC_  1024
#define NH_  8
#define NP_  4
#define DH_  48
#define NQ_  4096
#define NT_  730
#define NG_  729
#define GW_  27

typedef unsigned short u16;
typedef __attribute__((ext_vector_type(8))) short s8bf;   // 8 bf16 (4 VGPR)
typedef __attribute__((ext_vector_type(4))) float f32x4;  // MFMA accumulator

__device__ __forceinline__ float bf2f(u16 u) { return __uint_as_float(((unsigned)u) << 16); }
__device__ __forceinline__ u16 f2bf(float f) {
    __hip_bfloat16 h = __float2bfloat16(f);
    return *reinterpret_cast<u16*>(&h);
}
__device__ __forceinline__ float rd(const float* p) { return *p; }
__device__ __forceinline__ float rd(const u16* p)   { return bf2f(*p); }
__device__ __forceinline__ void  wr(float* p, float v) { *p = v; }
__device__ __forceinline__ void  wr(u16* p, float v)   { *p = f2bf(v); }
__device__ __forceinline__ void fmacc4(float4& o, const float4 v, float w) {
    o.x = fmaf(v.x, w, o.x); o.y = fmaf(v.y, w, o.y);
    o.z = fmaf(v.z, w, o.z); o.w = fmaf(v.w, w, o.w);
}
// LDS tile index (u16 units): [row][32 k] bf16, 64B row, XOR-swizzled per G4:
// byte ^= ((row&7)<<4). Bijective; spreads ds_read_b128 base-banks 8-wide.
__device__ __forceinline__ int lds_idx(int row, int slot) {
    return ((row << 5) + (slot << 3)) ^ ((row & 7) << 3);
}

// ---------------------------------------------------------------------------
// Tiled transpose: per batch src[R][C] -> dst[C][R]; Tin/Tout f32 or bf16.
// grid (C/32, R/32, B), block 256. Also used for weight f32[K,N]->bf16[N,K].
// ---------------------------------------------------------------------------
template <typename Tin, typename Tout>
__global__ __launch_bounds__(256) void transpose_kernel(
    const Tin* __restrict__ src, Tout* __restrict__ dst, int R, int Cc)
{
    __shared__ float tile[32][33];
    const int b  = blockIdx.z;
    const int c0 = blockIdx.x << 5;
    const int r0 = blockIdx.y << 5;
    const Tin*  s = src + (size_t)b * R * Cc;
    Tout*       d = dst + (size_t)b * R * Cc;
    const int tx = threadIdx.x & 31, ty = threadIdx.x >> 5;  // ty 0..7
#pragma unroll
    for (int i = 0; i < 32; i += 8)
        tile[ty + i][tx] = rd(s + (size_t)(r0 + ty + i) * Cc + c0 + tx);
    __syncthreads();
#pragma unroll
    for (int i = 0; i < 32; i += 8)
        wr(d + (size_t)(c0 + ty + i) * R + r0 + tx, tile[tx][ty + i]);
}

// ---------------------------------------------------------------------------
// Row LayerNorm: Tin in [rows][width] -> bf16 out. width <= 1024. block 256.
// ---------------------------------------------------------------------------
template <typename Tin>
__global__ __launch_bounds__(256) void ln_kernel(
    const Tin* __restrict__ x, const float* __restrict__ g, const float* __restrict__ be,
    u16* __restrict__ out, int width)
{
    __shared__ float buf[1024];
    __shared__ float red[4][2];
    const size_t row = blockIdx.x;
    const Tin* xr = x + row * width;
    const int t = threadIdx.x;
    float s = 0.f, ss = 0.f;
    for (int i = t; i < width; i += 256) {
        float v = rd(xr + i); buf[i] = v; s += v; ss += v * v;
    }
#pragma unroll
    for (int o = 32; o > 0; o >>= 1) { s += __shfl_down(s, o); ss += __shfl_down(ss, o); }
    const int wave = t >> 6, lane = t & 63;
    if (lane == 0) { red[wave][0] = s; red[wave][1] = ss; }
    __syncthreads();
    if (t == 0) {
        float S = 0.f, SS = 0.f;
        for (int w = 0; w < 4; ++w) { S += red[w][0]; SS += red[w][1]; }
        float m = S / width;
        float v = SS / width - m * m;
        red[0][0] = m; red[0][1] = rsqrtf(v + 1e-5f);
    }
    __syncthreads();
    const float m = red[0][0], rs = red[0][1];
    u16* op = out + row * width;
    for (int i = t; i < width; i += 256)
        op[i] = f2bf((buf[i] - m) * rs * g[i] + be[i]);
}

// ---------------------------------------------------------------------------
// MFMA GEMM, register prefetch + swizzled LDS:
// C[M,N] = act(A[M,K] @ W[K,N] + bias[N]); A bf16 [M,K]; Wt bf16 [N,K];
// bias f32; C f32 or bf16. BM=BN=128, BK=32, 256 thr = 4 waves 2x2,
// wave 64x64 out (4x4 frags of v_mfma_f32_16x16x32_bf16). K % 32 == 0.
// ACT: 0 none, 1 exact gelu, 2 relu.
// ---------------------------------------------------------------------------
template <int ACT, typename Tout>
__global__ __launch_bounds__(256) void mfma_gemm(
    const u16* __restrict__ A, const u16* __restrict__ Wt,
    const float* __restrict__ bias, Tout* __restrict__ C,
    int M, int N, int K)
{
    __shared__ u16 As[128 * 32];
    __shared__ u16 Bs[128 * 32];
    const int t    = threadIdx.x;
    const int m0   = blockIdx.x * 128;
    const int n0   = blockIdx.y * 128;
    const int lane = t & 63;
    const int wave = t >> 6;
    const int wm   = (wave >> 1) * 64;    // wave row offset in tile
    const int wn   = (wave & 1) * 64;     // wave col offset in tile
    const int lr   = lane & 15;
    const int lks  = lane >> 4;

    // staging map: thread t stages rows (srow, srow+64), k-slot sks
    const int srow = t >> 2, sks = t & 3;
    const bool aok0 = (m0 + srow)      < M;
    const bool aok1 = (m0 + 64 + srow) < M;
    const bool bok0 = (n0 + srow)      < N;
    const bool bok1 = (n0 + 64 + srow) < N;
    const u16* ap0 = A  + (size_t)(m0 + srow)      * K + sks * 8;
    const u16* ap1 = A  + (size_t)(m0 + 64 + srow) * K + sks * 8;
    const u16* bp0 = Wt + (size_t)(n0 + srow)      * K + sks * 8;
    const u16* bp1 = Wt + (size_t)(n0 + 64 + srow) * K + sks * 8;
    const int wi0 = lds_idx(srow, sks), wi1 = lds_idx(srow + 64, sks);

    f32x4 acc[4][4] = {};

    s8bf va0 = {}, va1 = {}, vb0 = {}, vb1 = {};
    if (aok0) va0 = *reinterpret_cast<const s8bf*>(ap0);
    if (aok1) va1 = *reinterpret_cast<const s8bf*>(ap1);
    if (bok0) vb0 = *reinterpret_cast<const s8bf*>(bp0);
    if (bok1) vb1 = *reinterpret_cast<const s8bf*>(bp1);

    for (int k0 = 0; k0 < K; k0 += 32) {
        *reinterpret_cast<s8bf*>(&As[wi0]) = va0;
        *reinterpret_cast<s8bf*>(&As[wi1]) = va1;
        *reinterpret_cast<s8bf*>(&Bs[wi0]) = vb0;
        *reinterpret_cast<s8bf*>(&Bs[wi1]) = vb1;
        __syncthreads();

        // prefetch next K-step while MFMA phase runs
        s8bf na0 = {}, na1 = {}, nb0 = {}, nb1 = {};
        if (k0 + 32 < K) {
            if (aok0) na0 = *reinterpret_cast<const s8bf*>(ap0 + k0 + 32);
            if (aok1) na1 = *reinterpret_cast<const s8bf*>(ap1 + k0 + 32);
            if (bok0) nb0 = *reinterpret_cast<const s8bf*>(bp0 + k0 + 32);
            if (bok1) nb1 = *reinterpret_cast<const s8bf*>(bp1 + k0 + 32);
        }

        s8bf af[4], bfr[4];
#pragma unroll
        for (int i = 0; i < 4; ++i) {
            af[i]  = *reinterpret_cast<const s8bf*>(&As[lds_idx(wm + i * 16 + lr, lks)]);
            bfr[i] = *reinterpret_cast<const s8bf*>(&Bs[lds_idx(wn + i * 16 + lr, lks)]);
        }
#pragma unroll
        for (int i = 0; i < 4; ++i)
#pragma unroll
            for (int j = 0; j < 4; ++j)
                acc[i][j] = __builtin_amdgcn_mfma_f32_16x16x32_bf16(af[i], bfr[j], acc[i][j], 0, 0, 0);
        __syncthreads();
        va0 = na0; va1 = na1; vb0 = nb0; vb1 = nb1;
    }

    // epilogue: D row = (lane>>4)*4 + r, col = lane&15 (m89-verified layout)
#pragma unroll
    for (int i = 0; i < 4; ++i) {
        const int gr0 = m0 + wm + i * 16 + (lane >> 4) * 4;
#pragma unroll
        for (int j = 0; j < 4; ++j) {
            const int gc = n0 + wn + j * 16 + lr;
            if (gc >= N) continue;
            const float bb = bias[gc];
#pragma unroll
            for (int r = 0; r < 4; ++r) {
                const int gr = gr0 + r;
                if (gr >= M) continue;
                float v = acc[i][j][r] + bb;
                if (ACT == 1) v = 0.5f * v * (1.0f + erff(v * 0.70710678118654752f));
                if (ACT == 2) v = v > 0.f ? v : 0.f;
                wr(C + (size_t)gr * N + gc, v);
            }
        }
    }
}

// ---------------------------------------------------------------------------
// Bias concat for fused off+attn projection: b_cat[0:64)=b_off, [64:96)=b_attn
// ---------------------------------------------------------------------------
__global__ __launch_bounds__(128) void concat_bias_kernel(
    const float* __restrict__ b_off, const float* __restrict__ b_attn,
    float* __restrict__ b_cat)
{
    const int t = threadIdx.x;
    if (t < 64) b_cat[t] = b_off[t];
    else if (t < 96) b_cat[t] = b_attn[t - 64];
}

// ---------------------------------------------------------------------------
// Sampler (float4-vectorized channels): per block QT=8 queries, 256 threads.
// proj [B*Nq,96] f32: cols 0..63 = offsets, 64..95 = attn logits.
// cpf [B,730,384] f32 channel-contiguous -> float4 gathers. out bf16.
// ---------------------------------------------------------------------------
__global__ __launch_bounds__(256) void sample_kernel(
    const float* __restrict__ proj, const float* __restrict__ cpf,
    u16* __restrict__ out)
{
    __shared__ float sAw[8][32];
    __shared__ float sX0[8][32], sY0[8][32], sWx1[8][32], sWy1[8][32];

    const int blk = blockIdx.x;
    const int b   = blk / (NQ_ / 8);
    const int q0  = (blk % (NQ_ / 8)) * 8;
    const int t   = threadIdx.x;

    {   // loc precompute: t -> (qq, point i), 256 = 8*32 exactly
        const int qq = t >> 5, i = t & 31;
        const size_t row = (size_t)b * NQ_ + q0 + qq;
        float ox = proj[row * 96 + 2 * i], oy = proj[row * 96 + 2 * i + 1];
        float gx = 2.f / (1.f + expf(-ox)) - 1.f;
        float gy = 2.f / (1.f + expf(-oy)) - 1.f;
        float ix = ((gx + 1.f) * (float)GW_ - 1.f) * 0.5f;
        float iy = ((gy + 1.f) * (float)GW_ - 1.f) * 0.5f;
        float x0 = floorf(ix), y0 = floorf(iy);
        sX0[qq][i] = x0; sY0[qq][i] = y0;
        sWx1[qq][i] = ix - x0; sWy1[qq][i] = iy - y0;
    }
    if (t < 64) {  // softmax over NP per (qq, h)
        const int qq = t >> 3, h = t & 7;
        const size_t row = (size_t)b * NQ_ + q0 + qq;
        const float* lg = proj + row * 96 + 64 + h * 4;
        float l0 = lg[0], l1 = lg[1], l2 = lg[2], l3 = lg[3];
        float m = fmaxf(fmaxf(l0, l1), fmaxf(l2, l3));
        float e0 = expf(l0 - m), e1 = expf(l1 - m), e2 = expf(l2 - m), e3 = expf(l3 - m);
        float inv = 1.f / (e0 + e1 + e2 + e3);
        sAw[qq][h * 4 + 0] = e0 * inv; sAw[qq][h * 4 + 1] = e1 * inv;
        sAw[qq][h * 4 + 2] = e2 * inv; sAw[qq][h * 4 + 3] = e3 * inv;
    }
    __syncthreads();

    // value[b, p, c] = cpf[b, 1+p, c]; float4 view: [729 tokens][96]
    const float4* vb4 = reinterpret_cast<const float4*>(cpf + (size_t)b * NT_ * D_ + D_);
    for (int idx = t; idx < 8 * 96; idx += 256) {   // 3 iterations
        const int qq = idx / 96, c4 = idx % 96, h = c4 / 12;   // 12 float4 per head
        float4 o = make_float4(0.f, 0.f, 0.f, 0.f);
#pragma unroll
        for (int p = 0; p < NP_; ++p) {
            const int i = h * 4 + p;
            float x0 = sX0[qq][i], y0 = sY0[qq][i];
            float wx1 = sWx1[qq][i], wy1 = sWy1[qq][i];
            float wx0 = 1.f - wx1, wy0 = 1.f - wy1;
            int xi = (int)x0, yi = (int)y0;
            bool vx0 = (xi >= 0) & (xi < GW_), vx1 = (xi + 1 >= 0) & (xi + 1 < GW_);
            bool vy0 = (yi >= 0) & (yi < GW_), vy1 = (yi + 1 >= 0) & (yi + 1 < GW_);
            const float aw = sAw[qq][i];
            if (vx0 & vy0) fmacc4(o, vb4[(size_t)(yi * GW_ + xi) * 96 + c4],       aw * wx0 * wy0);
            if (vx1 & vy0) fmacc4(o, vb4[(size_t)(yi * GW_ + xi + 1) * 96 + c4],   aw * wx1 * wy0);
            if (vx0 & vy1) fmacc4(o, vb4[(size_t)((yi + 1) * GW_ + xi) * 96 + c4], aw * wx0 * wy1);
            if (vx1 & vy1) fmacc4(o, vb4[(size_t)((yi + 1) * GW_ + xi + 1) * 96 + c4], aw * wx1 * wy1);
        }
        ushort4 pk;
        pk.x = f2bf(o.x); pk.y = f2bf(o.y); pk.z = f2bf(o.z); pk.w = f2bf(o.w);
        *reinterpret_cast<ushort4*>(&out[((size_t)b * NQ_ + q0 + qq) * D_ + c4 * 4]) = pk;
    }
}

// ---------------------------------------------------------------------------
// Gate reduce: gate[row] = sigmoid(dot(gh[row,0:96], Wg2) + bg2).
// One wave per row, 4 rows per 256-thread block.
// ---------------------------------------------------------------------------
__global__ __launch_bounds__(256) void gate_reduce_kernel(
    const float* __restrict__ gh, const float* __restrict__ Wg2,
    const float* __restrict__ bg2, float* __restrict__ gate_out)
{
    const int wave = threadIdx.x >> 6, lane = threadIdx.x & 63;
    const size_t row = (size_t)blockIdx.x * 4 + wave;
    const float* h = gh + row * 96;
    float s = h[lane] * Wg2[lane];
    if (lane < 32) s += h[64 + lane] * Wg2[64 + lane];
#pragma unroll
    for (int o = 32; o > 0; o >>= 1) s += __shfl_down(s, o);
    if (lane == 0) gate_out[row] = 1.f / (1.f + expf(-(s + bg2[0])));
}

// ---------------------------------------------------------------------------
// Fused output LN: x = vflat + gate*ffn; LN(ln_o) -> bf16 [B*Nq,384]
// ---------------------------------------------------------------------------
__global__ __launch_bounds__(128) void fused_ln_kernel(
    const u16* __restrict__ vflat, const float* __restrict__ gate,
    const u16* __restrict__ ffn,
    const float* __restrict__ g, const float* __restrict__ be,
    u16* __restrict__ outT)
{
    __shared__ float buf[D_];
    __shared__ float red[2][2];
    const size_t row = blockIdx.x;
    const int t = threadIdx.x;
    const float gv = gate[row];
    float s = 0.f, ss = 0.f;
    for (int i = t; i < D_; i += 128) {
        float v = bf2f(vflat[row * D_ + i]) + gv * bf2f(ffn[row * D_ + i]);
        buf[i] = v; s += v; ss += v * v;
    }
#pragma unroll
    for (int o = 32; o > 0; o >>= 1) { s += __shfl_down(s, o); ss += __shfl_down(ss, o); }
    const int wave = t >> 6, lane = t & 63;
    if (lane == 0) { red[wave][0] = s; red[wave][1] = ss; }
    __syncthreads();
    if (t == 0) {
        float S = red[0][0] + red[1][0], SS = red[0][1] + red[1][1];
        float m = S / (float)D_;
        float v = SS / (float)D_ - m * m;
        red[0][0] = m; red[0][1] = rsqrtf(v + 1e-5f);
    }
    __syncthreads();
    const float m = red[0][0], rs = red[0][1];
    u16* op = outT + row * D_;
    for (int i = t; i < D_; i += 128)
        op[i] = f2bf((buf[i] - m) * rs * g[i] + be[i]);
}

// ---------------------------------------------------------------------------
extern "C" void kernel_launch(void* const* d_in, const int* in_sizes, int n_in,
                              void* d_out, int out_size, void* d_ws, size_t ws_size,
                              hipStream_t stream)
{
    const float* visual = (const float*)d_in[0];
    const float* cut3r  = (const float*)d_in[1];
    const float* ln_v_g = (const float*)d_in[2];
    const float* ln_v_b = (const float*)d_in[3];
    const float* ln_c_g = (const float*)d_in[4];
    const float* ln_c_b = (const float*)d_in[5];
    const float* W_c1 = (const float*)d_in[6];
    const float* b_c1 = (const float*)d_in[7];
    const float* W_c2 = (const float*)d_in[8];
    const float* b_c2 = (const float*)d_in[9];
    const float* W_off = (const float*)d_in[10];
    const float* b_off = (const float*)d_in[11];
    const float* W_attn = (const float*)d_in[12];
    const float* b_attn = (const float*)d_in[13];
    const float* W_out = (const float*)d_in[14];
    const float* b_out = (const float*)d_in[15];
    const float* W_f1 = (const float*)d_in[16];
    const float* b_f1 = (const float*)d_in[17];
    const float* W_f2 = (const float*)d_in[18];
    const float* b_f2 = (const float*)d_in[19];
    const float* W_g1 = (const float*)d_in[20];
    const float* b_g1 = (const float*)d_in[21];
    const float* W_g2 = (const float*)d_in[22];
    const float* b_g2 = (const float*)d_in[23];
    const float* ln_o_g = (const float*)d_in[24];
    const float* ln_o_b = (const float*)d_in[25];

    // --- workspace layout (bytes), lifetime reuse; high-water ~84.5 MB ---
    // R0 [0, 25165824):        vflat bf16 [B,4096,384]
    // R1 [25165824, 50331648): cn -> vn -> attn_out -> fusedT  (bf16)
    // R2 [50331648, 75497472): chid -> dout -> ffn             (bf16)
    // R3 [75497472, 84467712): cpf f32 (steps 4-7); then wt_f1b/wt_f2b bf16
    char* ws = (char*)d_ws;
    u16*   vflat   = (u16*)(ws + 0);
    u16*   cn      = (u16*)(ws + 25165824);
    u16*   vn      = (u16*)(ws + 25165824);
    u16*   attn_out= (u16*)(ws + 25165824);
    u16*   fusedT  = (u16*)(ws + 25165824);
    u16*   chid    = (u16*)(ws + 50331648);
    u16*   dout    = (u16*)(ws + 50331648);
    u16*   ffn     = (u16*)(ws + 50331648);
    float* cpf     = (float*)(ws + 75497472);
    u16*   wt_f1b  = (u16*)(ws + 75497472);            // [1536][384] after cpf dead
    u16*   wt_f2b  = wt_f1b + 589824;                  // [384][1536]

    // --- d_out as scratch (fully overwritten by final steps) ---
    // proj_buf f32 [32768,96]  bytes [0, 12582912)       (steps 6-7)
    // b_cat    f32 [96]        bytes [12582912, 12583296)
    // gate_hid f32 [32768,96]  bytes [0, 12582912)       (step 9)
    // hidden  bf16 [16384,1536] bytes [0, 50331648)      (step 11, per chunk)
    // wt pool bf16 (~2.6 MB)   bytes [25165824, ...)     (steps 0-9, dies at 11)
    // out_gate f32 [32768]     bytes [50331648, 50462720) (step 9 -> final)
    float* dout_f   = (float*)d_out;
    float* proj_buf = dout_f;
    float* b_cat    = dout_f + 3145728;
    float* gate_hid = dout_f;
    u16*   hidden   = (u16*)d_out;
    char*  wtp      = (char*)d_out + 25165824;
    u16* wt_c1   = (u16*)wtp;                  // [768][1024]
    u16* wt_c2   = wt_c1 + 786432;             // [384][768]
    u16* wt_out  = wt_c2 + 294912;             // [384][384]
    u16* wt_g1   = wt_out + 147456;            // [96][384]
    u16* wt_off  = wt_g1 + 36864;              // [64][384]  \ contiguous [96][384]
    u16* wt_attn = wt_off + 24576;             // [32][384]  /
    float* out_fused = dout_f;
    float* out_gate  = dout_f + (size_t)B_ * D_ * NQ_;

    // 0. weight conversion (non-FFN): W f32 [K,N] -> Wt bf16 [N,K]
    hipLaunchKernelGGL((transpose_kernel<float, u16>), dim3(24, 32, 1), dim3(256), 0, stream, W_c1, wt_c1, 1024, 768);
    hipLaunchKernelGGL((transpose_kernel<float, u16>), dim3(12, 24, 1), dim3(256), 0, stream, W_c2, wt_c2, 768, 384);
    hipLaunchKernelGGL((transpose_kernel<float, u16>), dim3(12, 12, 1), dim3(256), 0, stream, W_out, wt_out, 384, 384);
    hipLaunchKernelGGL((transpose_kernel<float, u16>), dim3(3, 12, 1), dim3(256), 0, stream, W_g1, wt_g1, 384, 96);
    hipLaunchKernelGGL((transpose_kernel<float, u16>), dim3(2, 12, 1), dim3(256), 0, stream, W_off, wt_off, 384, 64);
    hipLaunchKernelGGL((transpose_kernel<float, u16>), dim3(1, 12, 1), dim3(256), 0, stream, W_attn, wt_attn, 384, 32);
    hipLaunchKernelGGL(concat_bias_kernel, dim3(1), dim3(128), 0, stream, b_off, b_attn, b_cat);

    // 1. visual f32 [B,384,4096] -> vflat bf16 [B,4096,384]
    hipLaunchKernelGGL((transpose_kernel<float, u16>), dim3(128, 12, 8), dim3(256), 0, stream,
                       visual, vflat, 384, 4096);
    // 2. LN(cut3r f32) -> cn bf16
    hipLaunchKernelGGL((ln_kernel<float>), dim3(5840), dim3(256), 0, stream,
                       cut3r, ln_c_g, ln_c_b, cn, 1024);
    // 3. gelu(cn @ W_c1 + b_c1) -> chid bf16   [5840 x 768 x 1024]
    hipLaunchKernelGGL((mfma_gemm<1, u16>), dim3(46, 6), dim3(256), 0, stream,
                       cn, wt_c1, b_c1, chid, 5840, 768, 1024);
    // 4. chid @ W_c2 + b_c2 -> cpf f32 [B,730,384]   [5840 x 384 x 768]
    hipLaunchKernelGGL((mfma_gemm<0, float>), dim3(46, 3), dim3(256), 0, stream,
                       chid, wt_c2, b_c2, cpf, 5840, 384, 768);
    // 5. LN(vflat bf16) -> vn bf16
    hipLaunchKernelGGL((ln_kernel<u16>), dim3(32768), dim3(256), 0, stream,
                       vflat, ln_v_g, ln_v_b, vn, 384);
    // 6. fused off+attn projection -> proj_buf f32 [32768 x 96 x 384]
    hipLaunchKernelGGL((mfma_gemm<0, float>), dim3(256, 1), dim3(256), 0, stream,
                       vn, wt_off, b_cat, proj_buf, 32768, 96, 384);
    // 7. sampler -> dout bf16 [B*Nq,384]  (cpf dead after)
    hipLaunchKernelGGL(sample_kernel, dim3(4096), dim3(256), 0, stream,
                       proj_buf, cpf, dout);
    // 8. dout @ W_out + b_out -> attn_out bf16   [32768 x 384 x 384]
    hipLaunchKernelGGL((mfma_gemm<0, u16>), dim3(256, 3), dim3(256), 0, stream,
                       dout, wt_out, b_out, attn_out, 32768, 384, 384);
    // 9. gate (before FFN; hidden will clobber wt pool + gate_hid):
    hipLaunchKernelGGL((mfma_gemm<2, float>), dim3(256, 1), dim3(256), 0, stream,
                       vflat, wt_g1, b_g1, gate_hid, 32768, 96, 384);
    hipLaunchKernelGGL(gate_reduce_kernel, dim3(8192), dim3(256), 0, stream,
                       gate_hid, W_g2, b_g2, out_gate);
    // 10. FFN weights -> ws (cpf region, now dead)
    hipLaunchKernelGGL((transpose_kernel<float, u16>), dim3(48, 12, 1), dim3(256), 0, stream, W_f1, wt_f1b, 384, 1536);
    hipLaunchKernelGGL((transpose_kernel<float, u16>), dim3(12, 48, 1), dim3(256), 0, stream, W_f2, wt_f2b, 1536, 384);
    // 11. FFN in 2 row-chunks of 16384; hidden bf16 [16384,1536] in d_out
    for (int c = 0; c < 2; ++c) {
        hipLaunchKernelGGL((mfma_gemm<1, u16>), dim3(128, 12), dim3(256), 0, stream,
                           attn_out + (size_t)c * 16384 * 384, wt_f1b, b_f1, hidden,
                           16384, 1536, 384);
        hipLaunchKernelGGL((mfma_gemm<0, u16>), dim3(128, 3), dim3(256), 0, stream,
                           hidden, wt_f2b, b_f2, ffn + (size_t)c * 16384 * 384,
                           16384, 384, 1536);
    }
    // 12. fused = LN(vflat + gate*ffn) -> fusedT bf16 [B,Nq,384]
    hipLaunchKernelGGL(fused_ln_kernel, dim3(32768), dim3(128), 0, stream,
                       vflat, out_gate, ffn, ln_o_g, ln_o_b, fusedT);
    // 13. fusedT bf16 [B,4096,384] -> d_out f32 [B,384,4096]
    hipLaunchKernelGGL((transpose_kernel<u16, float>), dim3(12, 128, 8), dim3(256), 0, stream,
                       fusedT, out_fused, 4096, 384);
}